// Round 1
// baseline (2321.096 us; speedup 1.0000x reference)
//
#include <hip/hip_runtime.h>
#include <math.h>

// Problem constants
#define Bn 16
#define Tn 512
#define Dn 512
#define Hn 8
#define DHn 64
#define COUTn 7
#define PREDn 96
#define Kn 16
#define DFFn 2048

// ---------------------------------------------------------------------------
// season = fourier_extrapolate(res, PRED, K) : one block per (b,d) column
// ---------------------------------------------------------------------------
__global__ __launch_bounds__(256) void season_kernel(
    const float* __restrict__ res, float* __restrict__ season) {
  int blk = blockIdx.x;          // 0..8191
  int b = blk >> 9;
  int d = blk & 511;
  int tid = threadIdx.x;

  __shared__ float col[512];
  __shared__ double ctab[512], stab[512];
  __shared__ double mag2s[256];
  __shared__ float reS[256], imS[256];
  __shared__ double redv[256];
  __shared__ int redk[256];
  __shared__ int selk[16];
  __shared__ float amp_[16], ph_[16];

  for (int m = tid; m < 512; m += 256) {
    double ang = (2.0 * M_PI / 512.0) * (double)m;
    ctab[m] = cos(ang);
    stab[m] = sin(ang);
    col[m] = res[((size_t)(b * 512 + m)) * 512 + d];
  }
  __syncthreads();

  int k = tid;
  if (k >= 1 && k <= 255) {
    double re = 0.0, im = 0.0;
    int m = 0;
    for (int t = 0; t < 512; ++t) {
      double x = (double)col[t];
      re += x * ctab[m];
      im -= x * stab[m];
      m += k;
      m &= 511;
    }
    mag2s[k] = re * re + im * im;
    reS[k] = (float)re;
    imS[k] = (float)im;
  } else {
    mag2s[0] = -1.0;
  }
  __syncthreads();

  // top-16 by magnitude (lowest index wins ties)
  for (int j = 0; j < 16; ++j) {
    redv[tid] = mag2s[tid];
    redk[tid] = tid;
    __syncthreads();
    for (int s = 128; s > 0; s >>= 1) {
      if (tid < s) {
        double ov = redv[tid + s];
        int ok = redk[tid + s];
        if (ov > redv[tid] || (ov == redv[tid] && ok < redk[tid])) {
          redv[tid] = ov;
          redk[tid] = ok;
        }
      }
      __syncthreads();
    }
    if (tid == 0) {
      int kk = redk[0];
      selk[j] = kk;
      mag2s[kk] = -2.0;
    }
    __syncthreads();
  }

  if (tid < 16) {
    int kk = selk[tid];
    float rr = reS[kk], ii = imS[kk];
    amp_[tid] = 2.0f * sqrtf(rr * rr + ii * ii) * (1.0f / 512.0f);
    ph_[tid] = atan2f(ii, rr);
  }
  __syncthreads();

  const float w0 = 6.283185307179586f / 512.0f;
  for (int t = tid; t < Tn + PREDn; t += 256) {
    float s = 0.f;
#pragma unroll
    for (int j = 0; j < 16; ++j) {
      int m = (selk[j] * t) & 511;
      s += amp_[j] * cosf((float)m * w0 + ph_[j]);
    }
    season[((size_t)(b * (Tn + PREDn) + t)) * 512 + d] = s;
  }
}

// ---------------------------------------------------------------------------
// res1 = res - season[:, :T]
// ---------------------------------------------------------------------------
__global__ __launch_bounds__(256) void res1_kernel(
    const float* __restrict__ res, const float* __restrict__ season,
    float* __restrict__ res1) {
  int idx = blockIdx.x * 256 + threadIdx.x;
  int stride = gridDim.x * 256;
  const int total = Bn * Tn * Dn;
  for (; idx < total; idx += stride) {
    int row = idx >> 9;       // b*512 + t
    int d = idx & 511;
    int b = row >> 9;
    int t = row & 511;
    res1[idx] = res[idx] - season[((size_t)(b * (Tn + PREDn) + t)) * 512 + d];
  }
}

// ---------------------------------------------------------------------------
// C[M,N] = A[M,Kd] @ W[N,Kd]^T (+ bias) (opt ReLU). 64x64 tile, 256 thr, 4x4.
// ---------------------------------------------------------------------------
template <int RELU>
__global__ __launch_bounds__(256) void gemm_bt(
    const float* __restrict__ A, const float* __restrict__ W,
    const float* __restrict__ bias, float* __restrict__ C,
    int M, int N, int Kd) {
  __shared__ float As[16][65];
  __shared__ float Bs[16][65];
  int tid = threadIdx.x;
  int tx = tid & 15, ty = tid >> 4;
  int m0 = blockIdx.y * 64, n0 = blockIdx.x * 64;
  int lr = tid >> 2;            // 0..63
  int lc = (tid & 3) * 4;       // 0,4,8,12

  float acc[4][4] = {};

  for (int k0 = 0; k0 < Kd; k0 += 16) {
    int gm = m0 + lr;
    float4 av = make_float4(0.f, 0.f, 0.f, 0.f);
    if (gm < M) av = *reinterpret_cast<const float4*>(&A[(size_t)gm * Kd + k0 + lc]);
    As[lc + 0][lr] = av.x;
    As[lc + 1][lr] = av.y;
    As[lc + 2][lr] = av.z;
    As[lc + 3][lr] = av.w;
    int gn = n0 + lr;
    float4 wv = make_float4(0.f, 0.f, 0.f, 0.f);
    if (gn < N) wv = *reinterpret_cast<const float4*>(&W[(size_t)gn * Kd + k0 + lc]);
    Bs[lc + 0][lr] = wv.x;
    Bs[lc + 1][lr] = wv.y;
    Bs[lc + 2][lr] = wv.z;
    Bs[lc + 3][lr] = wv.w;
    __syncthreads();
#pragma unroll
    for (int kk = 0; kk < 16; ++kk) {
      float a[4], bb[4];
#pragma unroll
      for (int i = 0; i < 4; ++i) a[i] = As[kk][ty * 4 + i];
#pragma unroll
      for (int j = 0; j < 4; ++j) bb[j] = Bs[kk][tx * 4 + j];
#pragma unroll
      for (int i = 0; i < 4; ++i)
#pragma unroll
        for (int j = 0; j < 4; ++j) acc[i][j] += a[i] * bb[j];
    }
    __syncthreads();
  }

#pragma unroll
  for (int i = 0; i < 4; ++i) {
    int gm = m0 + ty * 4 + i;
    if (gm >= M) continue;
#pragma unroll
    for (int j = 0; j < 4; ++j) {
      int gn = n0 + tx * 4 + j;
      if (gn >= N) continue;
      float v = acc[i][j] + (bias ? bias[gn] : 0.f);
      if (RELU) v = fmaxf(v, 0.f);
      C[(size_t)gm * N + gn] = v;
    }
  }
}

// ---------------------------------------------------------------------------
// growth EMA: diffs on the fly, writes gr[(b,0)]=v0_g, gr[(b,t+1)]=EMA state
// ---------------------------------------------------------------------------
__global__ __launch_bounds__(256) void ema_growth_kernel(
    const float* __restrict__ v, const float* __restrict__ z0,
    const float* __restrict__ v0_g, const float* __restrict__ sw_g,
    float* __restrict__ gr) {
  int gid = blockIdx.x * 256 + threadIdx.x;   // 0..8191
  int b = gid >> 9;
  int hd = gid & 511;
  int h = hd >> 6;
  float alpha = 1.0f / (1.0f + expf(-sw_g[h]));
  float one_m = 1.0f - alpha;
  float prev = z0[hd];
  float s = v0_g[hd];
  gr[((size_t)(b * (Tn + 1))) * 512 + hd] = s;
  for (int t = 0; t < Tn; ++t) {
    float cur = v[((size_t)(b * Tn + t)) * 512 + hd];
    float df = cur - prev;
    prev = cur;
    s = alpha * s + one_m * df;
    gr[((size_t)(b * (Tn + 1) + t + 1)) * 512 + hd] = s;
  }
}

// ---------------------------------------------------------------------------
// LayerNorm. MODE 0: val = X[row] - Y[b*513+t+1]   MODE 1: val = X[row]+Y[row]
// ---------------------------------------------------------------------------
template <int MODE>
__global__ __launch_bounds__(256) void ln_kernel(
    const float* __restrict__ X, const float* __restrict__ Y,
    const float* __restrict__ g, const float* __restrict__ bvec,
    float* __restrict__ out) {
  int row = blockIdx.x;    // b*512 + t
  int b = row >> 9;
  int t = row & 511;
  int tid = threadIdx.x;
  const float* xr = X + (size_t)row * 512;
  const float* yr = (MODE == 0) ? (Y + ((size_t)(b * (Tn + 1) + t + 1)) * 512)
                                : (Y + (size_t)row * 512);
  float2 xv = *reinterpret_cast<const float2*>(&xr[tid * 2]);
  float2 yv = *reinterpret_cast<const float2*>(&yr[tid * 2]);
  float v0 = (MODE == 0) ? (xv.x - yv.x) : (xv.x + yv.x);
  float v1 = (MODE == 0) ? (xv.y - yv.y) : (xv.y + yv.y);
  float s1 = v0 + v1;
  float s2 = v0 * v0 + v1 * v1;
  for (int o = 32; o > 0; o >>= 1) {
    s1 += __shfl_down(s1, o, 64);
    s2 += __shfl_down(s2, o, 64);
  }
  __shared__ float r1[4], r2[4];
  __shared__ float mu_s, rstd_s;
  int wv = tid >> 6, ln = tid & 63;
  if (ln == 0) { r1[wv] = s1; r2[wv] = s2; }
  __syncthreads();
  if (tid == 0) {
    float S1 = r1[0] + r1[1] + r1[2] + r1[3];
    float S2 = r2[0] + r2[1] + r2[2] + r2[3];
    float mu = S1 * (1.0f / 512.0f);
    float var = S2 * (1.0f / 512.0f) - mu * mu;
    mu_s = mu;
    rstd_s = rsqrtf(var + 1e-5f);
  }
  __syncthreads();
  float mu = mu_s, rstd = rstd_s;
  float2 gv = *reinterpret_cast<const float2*>(&g[tid * 2]);
  float2 bv = *reinterpret_cast<const float2*>(&bvec[tid * 2]);
  float o0 = (v0 - mu) * rstd * gv.x + bv.x;
  float o1 = (v1 - mu) * rstd * gv.y + bv.y;
  *reinterpret_cast<float2*>(&out[(size_t)row * 512 + tid * 2]) =
      make_float2(o0, o1);
}

// ---------------------------------------------------------------------------
// 7-wide projection: out[(b*512+t)*7+c] = X[(b*strB+off+t)] . Wc[c] + bc[c]
// one wave per (b,t)
// ---------------------------------------------------------------------------
__global__ __launch_bounds__(64) void proj7_kernel(
    const float* __restrict__ X, int strB, int off,
    const float* __restrict__ Wc, const float* __restrict__ bc,
    float* __restrict__ outp) {
  int bt = blockIdx.x;      // 0..8191
  int b = bt >> 9;
  int t = bt & 511;
  int lane = threadIdx.x;
  const float* row = X + ((size_t)(b * strB + off + t)) * 512;
  float x[8];
#pragma unroll
  for (int i = 0; i < 8; ++i) x[i] = row[lane + 64 * i];
#pragma unroll
  for (int c = 0; c < 7; ++c) {
    float s = 0.f;
#pragma unroll
    for (int i = 0; i < 8; ++i) s += x[i] * Wc[c * 512 + lane + 64 * i];
    for (int o = 32; o > 0; o >>= 1) s += __shfl_down(s, o, 64);
    if (lane == 0) outp[((size_t)bt) * 7 + c] = s + bc[c];
  }
}

// ---------------------------------------------------------------------------
// level EMA with aux: one thread per (b,c)
// ---------------------------------------------------------------------------
__global__ __launch_bounds__(128) void lvl_kernel(
    const float* __restrict__ level, const float* __restrict__ sp,
    const float* __restrict__ gp, const float* __restrict__ v0_l,
    const float* __restrict__ sw_l, float* __restrict__ out_lvl) {
  int tid = blockIdx.x * 128 + threadIdx.x;
  if (tid >= Bn * COUTn) return;
  int b = tid / COUTn;
  int c = tid % COUTn;
  float alpha = 1.0f / (1.0f + expf(-sw_l[c]));
  float one_m = 1.0f - alpha;
  float s = v0_l[c];
  for (int t = 0; t < Tn; ++t) {
    size_t i = ((size_t)(b * Tn + t)) * COUTn + c;
    float esv = level[i] - sp[i];
    s = alpha * s + one_m * esv + alpha * gp[i];
    out_lvl[i] = s;
  }
}

// ---------------------------------------------------------------------------
extern "C" void kernel_launch(void* const* d_in, const int* in_sizes, int n_in,
                              void* d_out, int out_size, void* d_ws,
                              size_t ws_size, hipStream_t stream) {
  const float* res = (const float*)d_in[0];
  const float* level = (const float*)d_in[1];
  const float* Wi = (const float*)d_in[2];
  const float* bi = (const float*)d_in[3];
  const float* z0 = (const float*)d_in[4];
  const float* v0_g = (const float*)d_in[5];
  const float* sw_g = (const float*)d_in[6];
  const float* Wo = (const float*)d_in[7];
  const float* bo = (const float*)d_in[8];
  const float* W1 = (const float*)d_in[9];
  const float* W2 = (const float*)d_in[10];
  const float* g1 = (const float*)d_in[11];
  const float* b1 = (const float*)d_in[12];
  const float* g2 = (const float*)d_in[13];
  const float* b2 = (const float*)d_in[14];
  const float* Wg = (const float*)d_in[15];
  const float* bg = (const float*)d_in[16];
  const float* Wse = (const float*)d_in[17];
  const float* bs = (const float*)d_in[18];
  const float* v0_l = (const float*)d_in[19];
  const float* sw_l = (const float*)d_in[20];

  float* out = (float*)d_out;
  float* out_h = out;                               // 16*512*512
  float* out_lvl = out + 4194304;                   // 16*512*7
  float* out_growth = out + 4251648;                // 16*513*512
  float* out_season = out + 8454144;                // 16*608*512

  float* wsf = (float*)d_ws;
  float* res1 = wsf;                  // 4,194,304
  float* vbuf = wsf + 4194304;        // 4,194,304
  float* grbuf = wsf + 8388608;       // 4,202,496
  float* h1 = wsf + 12591104;         // 4,194,304  (ws end: 16,785,408 fl = 67.1MB)
  float* ff1 = res1;                  // reuse (res1 dead after ln<0>)
  float* ff2 = vbuf;                  // reuse (v dead after ema_growth)
  float* gpb = grbuf;                 // reuse (gr dead after growth gemm)
  float* spb = grbuf + 57344;

  // 1. season
  hipLaunchKernelGGL(season_kernel, dim3(Bn * Dn), dim3(256), 0, stream,
                     res, out_season);
  // 2. res1 = res - season[:, :T]
  hipLaunchKernelGGL(res1_kernel, dim3(4096), dim3(256), 0, stream,
                     res, out_season, res1);
  // 3. v = res1 @ Wi^T + bi
  hipLaunchKernelGGL((gemm_bt<0>), dim3(8, 128), dim3(256), 0, stream,
                     res1, Wi, bi, vbuf, Bn * Tn, 512, 512);
  // 4. growth EMA -> gr
  hipLaunchKernelGGL(ema_growth_kernel, dim3(32), dim3(256), 0, stream,
                     vbuf, z0, v0_g, sw_g, grbuf);
  // 5. growth = gr @ Wo^T + bo  (direct to output)
  hipLaunchKernelGGL((gemm_bt<0>), dim3(8, 129), dim3(256), 0, stream,
                     grbuf, Wo, bo, out_growth, Bn * (Tn + 1), 512, 512);
  // 6. h1 = LN(res1 - growth[:,1:])
  hipLaunchKernelGGL((ln_kernel<0>), dim3(Bn * Tn), dim3(256), 0, stream,
                     res1, out_growth, g1, b1, h1);
  // 7. FFN (chunked over M to bound workspace)
  for (int c = 0; c < 4; ++c) {
    const float* hA = h1 + (size_t)c * 2048 * 512;
    hipLaunchKernelGGL((gemm_bt<1>), dim3(32, 32), dim3(256), 0, stream,
                       hA, W1, (const float*)nullptr, ff1, 2048, DFFn, 512);
    hipLaunchKernelGGL((gemm_bt<0>), dim3(8, 32), dim3(256), 0, stream,
                       ff1, W2, (const float*)nullptr,
                       ff2 + (size_t)c * 2048 * 512, 2048, 512, DFFn);
  }
  // 8. h = LN(h1 + ff)
  hipLaunchKernelGGL((ln_kernel<1>), dim3(Bn * Tn), dim3(256), 0, stream,
                     h1, ff2, g2, b2, out_h);
  // 9. gp / sp projections
  hipLaunchKernelGGL(proj7_kernel, dim3(Bn * Tn), dim3(64), 0, stream,
                     out_growth, Tn + 1, 1, Wg, bg, gpb);
  hipLaunchKernelGGL(proj7_kernel, dim3(Bn * Tn), dim3(64), 0, stream,
                     out_season, Tn + PREDn, 0, Wse, bs, spb);
  // 10. level EMA
  hipLaunchKernelGGL(lvl_kernel, dim3(1), dim3(128), 0, stream,
                     level, spb, gpb, v0_l, sw_l, out_lvl);

  (void)in_sizes; (void)n_in; (void)out_size; (void)ws_size;
}

// Round 2
// 1740.346 us; speedup vs baseline: 1.3337x; 1.3337x over previous
//
#include <hip/hip_runtime.h>
#include <math.h>

// Problem constants
#define Bn 16
#define Tn 512
#define Dn 512
#define Hn 8
#define DHn 64
#define COUTn 7
#define PREDn 96
#define Kn 16
#define DFFn 2048

// ---------------------------------------------------------------------------
// Twiddle init: twc/tws[k][t] = cos/sin(2*pi*((k*t)&511)/512) in f64,
// plus 512-entry f32 synthesis tables.
// ---------------------------------------------------------------------------
__global__ __launch_bounds__(256) void twiddle_init(
    double* __restrict__ twc, double* __restrict__ tws,
    float* __restrict__ c512, float* __restrict__ s512) {
  int idx = blockIdx.x * 256 + threadIdx.x;   // 0..131071
  int k = idx >> 9, t = idx & 511;
  int m = (k * t) & 511;
  double ang = (double)m * (M_PI / 256.0);
  twc[idx] = cos(ang);
  tws[idx] = sin(ang);
  if (idx < 512) {
    double a2 = (double)idx * (M_PI / 256.0);
    c512[idx] = (float)cos(a2);
    s512[idx] = (float)sin(a2);
  }
}

// ---------------------------------------------------------------------------
// DFT GEMM (f64 accumulate): Fre[b][k][d] =  sum_t twc[k][t]*res[b][t][d]
//                            Fim[b][k][d] = -sum_t tws[k][t]*res[b][t][d]
// 64x64 tile (k x d), K-loop over t, 256 threads, 4x4 microtile.
// ---------------------------------------------------------------------------
__global__ __launch_bounds__(256) void dft_gemm(
    const double* __restrict__ twc, const double* __restrict__ tws,
    const float* __restrict__ res,
    double* __restrict__ Fre, double* __restrict__ Fim) {
  int b = blockIdx.z;
  int k0 = blockIdx.y * 64;
  int d0 = blockIdx.x * 64;
  __shared__ double Ac[16][66];
  __shared__ double As_[16][66];
  __shared__ float Bs[16][68];
  int tid = threadIdx.x;
  int tx = tid & 15, ty = tid >> 4;
  int lr = tid >> 2;            // 0..63 : k-row within tile
  int lc = (tid & 3) * 4;       // 0,4,8,12 : t-offset
  int br = tid >> 4;            // 0..15 : t-row
  int bc = (tid & 15) * 4;      // 0..60 : d-offset

  double accR[4][4] = {};
  double accI[4][4] = {};
  const float* resb = res + (size_t)b * (Tn * Dn);

  for (int t0 = 0; t0 < 512; t0 += 16) {
    const double* ac = &twc[(size_t)(k0 + lr) * 512 + t0 + lc];
    const double* as = &tws[(size_t)(k0 + lr) * 512 + t0 + lc];
    double2 c01 = *reinterpret_cast<const double2*>(ac);
    double2 c23 = *reinterpret_cast<const double2*>(ac + 2);
    double2 s01 = *reinterpret_cast<const double2*>(as);
    double2 s23 = *reinterpret_cast<const double2*>(as + 2);
    Ac[lc + 0][lr] = c01.x; Ac[lc + 1][lr] = c01.y;
    Ac[lc + 2][lr] = c23.x; Ac[lc + 3][lr] = c23.y;
    As_[lc + 0][lr] = s01.x; As_[lc + 1][lr] = s01.y;
    As_[lc + 2][lr] = s23.x; As_[lc + 3][lr] = s23.y;
    float4 bv = *reinterpret_cast<const float4*>(
        &resb[(size_t)(t0 + br) * 512 + d0 + bc]);
    *reinterpret_cast<float4*>(&Bs[br][bc]) = bv;
    __syncthreads();
#pragma unroll
    for (int kk = 0; kk < 16; ++kk) {
      double a_c[4], a_s[4], bb[4];
#pragma unroll
      for (int i = 0; i < 4; ++i) {
        a_c[i] = Ac[kk][ty * 4 + i];
        a_s[i] = As_[kk][ty * 4 + i];
      }
#pragma unroll
      for (int j = 0; j < 4; ++j) bb[j] = (double)Bs[kk][tx * 4 + j];
#pragma unroll
      for (int i = 0; i < 4; ++i)
#pragma unroll
        for (int j = 0; j < 4; ++j) {
          accR[i][j] += a_c[i] * bb[j];
          accI[i][j] -= a_s[i] * bb[j];
        }
    }
    __syncthreads();
  }
#pragma unroll
  for (int i = 0; i < 4; ++i) {
    int k = k0 + ty * 4 + i;
#pragma unroll
    for (int j = 0; j < 4; ++j) {
      int d = d0 + tx * 4 + j;
      size_t o = ((size_t)b * 256 + k) * 512 + d;
      Fre[o] = accR[i][j];
      Fim[o] = accI[i][j];
    }
  }
}

// ---------------------------------------------------------------------------
// Top-16 per column (one wave per (b,d)). Writes kidx/cj/sj as [b][16][512].
// cj = 2*re/512, sj = 2*im/512 (amp*cos(th+ph) == cj*cos(th) - sj*sin(th))
// ---------------------------------------------------------------------------
__global__ __launch_bounds__(64) void topk_kernel(
    const double* __restrict__ Fre, const double* __restrict__ Fim,
    int* __restrict__ kidx, float* __restrict__ cjb, float* __restrict__ sjb) {
  int blk = blockIdx.x;          // 0..8191
  int b = blk >> 9;
  int d = blk & 511;
  int lane = threadIdx.x;

  double re[4], im[4], m2[4];
#pragma unroll
  for (int i = 0; i < 4; ++i) {
    int k = 1 + lane + 64 * i;
    if (k <= 255) {
      size_t o = ((size_t)b * 256 + k) * 512 + d;
      re[i] = Fre[o];
      im[i] = Fim[o];
      m2[i] = re[i] * re[i] + im[i] * im[i];
    } else {
      re[i] = 0.0; im[i] = 0.0; m2[i] = -1.0;
    }
  }

  for (int j = 0; j < 16; ++j) {
    // local argmax over up to 4 candidates
    double bm = -2.0; int bk = 1 << 20;
#pragma unroll
    for (int i = 0; i < 4; ++i) {
      int k = 1 + lane + 64 * i;
      if (m2[i] > bm || (m2[i] == bm && k < bk)) { bm = m2[i]; bk = k; }
    }
    // wave argmax (mag desc, index asc on ties)
    for (int o = 32; o > 0; o >>= 1) {
      double om = __shfl_down(bm, o, 64);
      int ok = __shfl_down(bk, o, 64);
      if (om > bm || (om == bm && ok < bk)) { bm = om; bk = ok; }
    }
    bk = __shfl(bk, 0, 64);
    // owner writes, everyone invalidates
#pragma unroll
    for (int i = 0; i < 4; ++i) {
      int k = 1 + lane + 64 * i;
      if (k == bk) {
        size_t o = ((size_t)b * 16 + j) * 512 + d;
        kidx[o] = k;
        cjb[o] = (float)(re[i] * (2.0 / 512.0));
        sjb[o] = (float)(im[i] * (2.0 / 512.0));
        m2[i] = -1.0;
      }
    }
  }
}

// ---------------------------------------------------------------------------
// Synthesis + res1. Block = (t-tile of 16) x b ; 512 threads = one per d.
// season[b][t][d] = sum_j cj*cos(2pi*m/512) - sj*sin(...),  m=(k_j*t)&511
// res1[b][t][d] = res - season   (t < 512)
// ---------------------------------------------------------------------------
__global__ __launch_bounds__(512) void synth_kernel(
    const int* __restrict__ kidx, const float* __restrict__ cjb,
    const float* __restrict__ sjb, const float* __restrict__ c512,
    const float* __restrict__ s512, const float* __restrict__ res,
    float* __restrict__ season, float* __restrict__ res1) {
  int b = blockIdx.y;
  int t0 = blockIdx.x * 16;
  int d = threadIdx.x;

  __shared__ float ct[512], st[512];
  ct[d] = c512[d];
  st[d] = s512[d];
  __syncthreads();

  int kk[16];
  float cw[16], sw[16];
#pragma unroll
  for (int j = 0; j < 16; ++j) {
    size_t o = ((size_t)b * 16 + j) * 512 + d;
    kk[j] = kidx[o];
    cw[j] = cjb[o];
    sw[j] = sjb[o];
  }

  for (int tt = 0; tt < 16; ++tt) {
    int t = t0 + tt;
    float acc = 0.f;
#pragma unroll
    for (int j = 0; j < 16; ++j) {
      int m = (kk[j] * t) & 511;
      acc += cw[j] * ct[m] - sw[j] * st[m];
    }
    season[((size_t)(b * (Tn + PREDn) + t)) * 512 + d] = acc;
    if (t < Tn) {
      size_t o = ((size_t)(b * Tn + t)) * 512 + d;
      res1[o] = res[o] - acc;
    }
  }
}

// ---------------------------------------------------------------------------
// C[M,N] = A[M,Kd] @ W[N,Kd]^T (+ bias) (opt ReLU). 64x64 tile, 256 thr, 4x4.
// ---------------------------------------------------------------------------
template <int RELU>
__global__ __launch_bounds__(256) void gemm_bt(
    const float* __restrict__ A, const float* __restrict__ W,
    const float* __restrict__ bias, float* __restrict__ C,
    int M, int N, int Kd) {
  __shared__ float As[16][65];
  __shared__ float Bs[16][65];
  int tid = threadIdx.x;
  int tx = tid & 15, ty = tid >> 4;
  int m0 = blockIdx.y * 64, n0 = blockIdx.x * 64;
  int lr = tid >> 2;            // 0..63
  int lc = (tid & 3) * 4;       // 0,4,8,12

  float acc[4][4] = {};

  for (int k0 = 0; k0 < Kd; k0 += 16) {
    int gm = m0 + lr;
    float4 av = make_float4(0.f, 0.f, 0.f, 0.f);
    if (gm < M) av = *reinterpret_cast<const float4*>(&A[(size_t)gm * Kd + k0 + lc]);
    As[lc + 0][lr] = av.x;
    As[lc + 1][lr] = av.y;
    As[lc + 2][lr] = av.z;
    As[lc + 3][lr] = av.w;
    int gn = n0 + lr;
    float4 wv = make_float4(0.f, 0.f, 0.f, 0.f);
    if (gn < N) wv = *reinterpret_cast<const float4*>(&W[(size_t)gn * Kd + k0 + lc]);
    Bs[lc + 0][lr] = wv.x;
    Bs[lc + 1][lr] = wv.y;
    Bs[lc + 2][lr] = wv.z;
    Bs[lc + 3][lr] = wv.w;
    __syncthreads();
#pragma unroll
    for (int kk = 0; kk < 16; ++kk) {
      float a[4], bb[4];
#pragma unroll
      for (int i = 0; i < 4; ++i) a[i] = As[kk][ty * 4 + i];
#pragma unroll
      for (int j = 0; j < 4; ++j) bb[j] = Bs[kk][tx * 4 + j];
#pragma unroll
      for (int i = 0; i < 4; ++i)
#pragma unroll
        for (int j = 0; j < 4; ++j) acc[i][j] += a[i] * bb[j];
    }
    __syncthreads();
  }

#pragma unroll
  for (int i = 0; i < 4; ++i) {
    int gm = m0 + ty * 4 + i;
    if (gm >= M) continue;
#pragma unroll
    for (int j = 0; j < 4; ++j) {
      int gn = n0 + tx * 4 + j;
      if (gn >= N) continue;
      float v = acc[i][j] + (bias ? bias[gn] : 0.f);
      if (RELU) v = fmaxf(v, 0.f);
      C[(size_t)gm * N + gn] = v;
    }
  }
}

// ---------------------------------------------------------------------------
// growth EMA: diffs on the fly, writes gr[(b,0)]=v0_g, gr[(b,t+1)]=EMA state
// ---------------------------------------------------------------------------
__global__ __launch_bounds__(256) void ema_growth_kernel(
    const float* __restrict__ v, const float* __restrict__ z0,
    const float* __restrict__ v0_g, const float* __restrict__ sw_g,
    float* __restrict__ gr) {
  int gid = blockIdx.x * 256 + threadIdx.x;   // 0..8191
  int b = gid >> 9;
  int hd = gid & 511;
  int h = hd >> 6;
  float alpha = 1.0f / (1.0f + expf(-sw_g[h]));
  float one_m = 1.0f - alpha;
  float prev = z0[hd];
  float s = v0_g[hd];
  gr[((size_t)(b * (Tn + 1))) * 512 + hd] = s;
  for (int t = 0; t < Tn; ++t) {
    float cur = v[((size_t)(b * Tn + t)) * 512 + hd];
    float df = cur - prev;
    prev = cur;
    s = alpha * s + one_m * df;
    gr[((size_t)(b * (Tn + 1) + t + 1)) * 512 + hd] = s;
  }
}

// ---------------------------------------------------------------------------
// LayerNorm. MODE 0: val = X[row] - Y[b*513+t+1]   MODE 1: val = X[row]+Y[row]
// ---------------------------------------------------------------------------
template <int MODE>
__global__ __launch_bounds__(256) void ln_kernel(
    const float* __restrict__ X, const float* __restrict__ Y,
    const float* __restrict__ g, const float* __restrict__ bvec,
    float* __restrict__ out) {
  int row = blockIdx.x;    // b*512 + t
  int b = row >> 9;
  int t = row & 511;
  int tid = threadIdx.x;
  const float* xr = X + (size_t)row * 512;
  const float* yr = (MODE == 0) ? (Y + ((size_t)(b * (Tn + 1) + t + 1)) * 512)
                                : (Y + (size_t)row * 512);
  float2 xv = *reinterpret_cast<const float2*>(&xr[tid * 2]);
  float2 yv = *reinterpret_cast<const float2*>(&yr[tid * 2]);
  float v0 = (MODE == 0) ? (xv.x - yv.x) : (xv.x + yv.x);
  float v1 = (MODE == 0) ? (xv.y - yv.y) : (xv.y + yv.y);
  float s1 = v0 + v1;
  float s2 = v0 * v0 + v1 * v1;
  for (int o = 32; o > 0; o >>= 1) {
    s1 += __shfl_down(s1, o, 64);
    s2 += __shfl_down(s2, o, 64);
  }
  __shared__ float r1[4], r2[4];
  __shared__ float mu_s, rstd_s;
  int wv = tid >> 6, ln = tid & 63;
  if (ln == 0) { r1[wv] = s1; r2[wv] = s2; }
  __syncthreads();
  if (tid == 0) {
    float S1 = r1[0] + r1[1] + r1[2] + r1[3];
    float S2 = r2[0] + r2[1] + r2[2] + r2[3];
    float mu = S1 * (1.0f / 512.0f);
    float var = S2 * (1.0f / 512.0f) - mu * mu;
    mu_s = mu;
    rstd_s = rsqrtf(var + 1e-5f);
  }
  __syncthreads();
  float mu = mu_s, rstd = rstd_s;
  float2 gv = *reinterpret_cast<const float2*>(&g[tid * 2]);
  float2 bv = *reinterpret_cast<const float2*>(&bvec[tid * 2]);
  float o0 = (v0 - mu) * rstd * gv.x + bv.x;
  float o1 = (v1 - mu) * rstd * gv.y + bv.y;
  *reinterpret_cast<float2*>(&out[(size_t)row * 512 + tid * 2]) =
      make_float2(o0, o1);
}

// ---------------------------------------------------------------------------
// 7-wide projection: out[(b*512+t)*7+c] = X[(b*strB+off+t)] . Wc[c] + bc[c]
// one wave per (b,t)
// ---------------------------------------------------------------------------
__global__ __launch_bounds__(64) void proj7_kernel(
    const float* __restrict__ X, int strB, int off,
    const float* __restrict__ Wc, const float* __restrict__ bc,
    float* __restrict__ outp) {
  int bt = blockIdx.x;      // 0..8191
  int b = bt >> 9;
  int t = bt & 511;
  int lane = threadIdx.x;
  const float* row = X + ((size_t)(b * strB + off + t)) * 512;
  float x[8];
#pragma unroll
  for (int i = 0; i < 8; ++i) x[i] = row[lane + 64 * i];
#pragma unroll
  for (int c = 0; c < 7; ++c) {
    float s = 0.f;
#pragma unroll
    for (int i = 0; i < 8; ++i) s += x[i] * Wc[c * 512 + lane + 64 * i];
    for (int o = 32; o > 0; o >>= 1) s += __shfl_down(s, o, 64);
    if (lane == 0) outp[((size_t)bt) * 7 + c] = s + bc[c];
  }
}

// ---------------------------------------------------------------------------
// level EMA with aux: one thread per (b,c)
// ---------------------------------------------------------------------------
__global__ __launch_bounds__(128) void lvl_kernel(
    const float* __restrict__ level, const float* __restrict__ sp,
    const float* __restrict__ gp, const float* __restrict__ v0_l,
    const float* __restrict__ sw_l, float* __restrict__ out_lvl) {
  int tid = blockIdx.x * 128 + threadIdx.x;
  if (tid >= Bn * COUTn) return;
  int b = tid / COUTn;
  int c = tid % COUTn;
  float alpha = 1.0f / (1.0f + expf(-sw_l[c]));
  float one_m = 1.0f - alpha;
  float s = v0_l[c];
  for (int t = 0; t < Tn; ++t) {
    size_t i = ((size_t)(b * Tn + t)) * COUTn + c;
    float esv = level[i] - sp[i];
    s = alpha * s + one_m * esv + alpha * gp[i];
    out_lvl[i] = s;
  }
}

// ---------------------------------------------------------------------------
extern "C" void kernel_launch(void* const* d_in, const int* in_sizes, int n_in,
                              void* d_out, int out_size, void* d_ws,
                              size_t ws_size, hipStream_t stream) {
  const float* res = (const float*)d_in[0];
  const float* level = (const float*)d_in[1];
  const float* Wi = (const float*)d_in[2];
  const float* bi = (const float*)d_in[3];
  const float* z0 = (const float*)d_in[4];
  const float* v0_g = (const float*)d_in[5];
  const float* sw_g = (const float*)d_in[6];
  const float* Wo = (const float*)d_in[7];
  const float* bo = (const float*)d_in[8];
  const float* W1 = (const float*)d_in[9];
  const float* W2 = (const float*)d_in[10];
  const float* g1 = (const float*)d_in[11];
  const float* b1 = (const float*)d_in[12];
  const float* g2 = (const float*)d_in[13];
  const float* b2 = (const float*)d_in[14];
  const float* Wg = (const float*)d_in[15];
  const float* bg = (const float*)d_in[16];
  const float* Wse = (const float*)d_in[17];
  const float* bs = (const float*)d_in[18];
  const float* v0_l = (const float*)d_in[19];
  const float* sw_l = (const float*)d_in[20];

  float* out = (float*)d_out;
  float* out_h = out;                               // 16*512*512
  float* out_lvl = out + 4194304;                   // 16*512*7
  float* out_growth = out + 4251648;                // 16*513*512
  float* out_season = out + 8454144;                // 16*608*512

  float* wsf = (float*)d_ws;
  // persistent-phase buffers (same layout as round 1)
  float* res1 = wsf;                  // 4,194,304 fl
  float* vbuf = wsf + 4194304;        // 4,194,304 fl
  float* grbuf = wsf + 8388608;       // 4,202,496 fl
  float* h1 = wsf + 12591104;         // 4,194,304 fl (ws end 16,785,408 fl)
  float* ff1 = res1;                  // reuse (res1 dead after ln<0>)
  float* ff2 = vbuf;                  // reuse (v dead after ema_growth)
  float* gpb = grbuf;                 // reuse (gr dead after growth gemm)
  float* spb = grbuf + 57344;

  // season-phase overlays (all dead before their hosts are written):
  double* Fre = (double*)(wsf + 4194304);       // 2,097,152 f64 (over vbuf)
  double* Fim = (double*)(wsf + 8388608);       // 2,097,152 f64 (over grbuf)
  double* twc = (double*)(wsf + 12591104);      // 131,072 f64 (over h1)
  double* tws = (double*)(wsf + 12853248);      // 131,072 f64
  float* c512 = wsf + 13115392;                 // 512 fl
  float* s512 = wsf + 13115904;                 // 512 fl
  int* kidx = (int*)(wsf + 13116416);           // 131,072
  float* cjb = wsf + 13247488;                  // 131,072
  float* sjb = wsf + 13378560;                  // 131,072 (end 13,509,632)

  // 1. season: twiddle -> DFT gemm -> topk -> synthesis (+res1 fused)
  hipLaunchKernelGGL(twiddle_init, dim3(512), dim3(256), 0, stream,
                     twc, tws, c512, s512);
  hipLaunchKernelGGL(dft_gemm, dim3(8, 4, 16), dim3(256), 0, stream,
                     twc, tws, res, Fre, Fim);
  hipLaunchKernelGGL(topk_kernel, dim3(Bn * Dn), dim3(64), 0, stream,
                     Fre, Fim, kidx, cjb, sjb);
  hipLaunchKernelGGL(synth_kernel, dim3(38, 16), dim3(512), 0, stream,
                     kidx, cjb, sjb, c512, s512, res, out_season, res1);
  // 3. v = res1 @ Wi^T + bi
  hipLaunchKernelGGL((gemm_bt<0>), dim3(8, 128), dim3(256), 0, stream,
                     res1, Wi, bi, vbuf, Bn * Tn, 512, 512);
  // 4. growth EMA -> gr
  hipLaunchKernelGGL(ema_growth_kernel, dim3(32), dim3(256), 0, stream,
                     vbuf, z0, v0_g, sw_g, grbuf);
  // 5. growth = gr @ Wo^T + bo  (direct to output)
  hipLaunchKernelGGL((gemm_bt<0>), dim3(8, 129), dim3(256), 0, stream,
                     grbuf, Wo, bo, out_growth, Bn * (Tn + 1), 512, 512);
  // 6. h1 = LN(res1 - growth[:,1:])
  hipLaunchKernelGGL((ln_kernel<0>), dim3(Bn * Tn), dim3(256), 0, stream,
                     res1, out_growth, g1, b1, h1);
  // 7. FFN (chunked over M to bound workspace)
  for (int c = 0; c < 4; ++c) {
    const float* hA = h1 + (size_t)c * 2048 * 512;
    hipLaunchKernelGGL((gemm_bt<1>), dim3(32, 32), dim3(256), 0, stream,
                       hA, W1, (const float*)nullptr, ff1, 2048, DFFn, 512);
    hipLaunchKernelGGL((gemm_bt<0>), dim3(8, 32), dim3(256), 0, stream,
                       ff1, W2, (const float*)nullptr,
                       ff2 + (size_t)c * 2048 * 512, 2048, 512, DFFn);
  }
  // 8. h = LN(h1 + ff)
  hipLaunchKernelGGL((ln_kernel<1>), dim3(Bn * Tn), dim3(256), 0, stream,
                     h1, ff2, g2, b2, out_h);
  // 9. gp / sp projections
  hipLaunchKernelGGL(proj7_kernel, dim3(Bn * Tn), dim3(64), 0, stream,
                     out_growth, Tn + 1, 1, Wg, bg, gpb);
  hipLaunchKernelGGL(proj7_kernel, dim3(Bn * Tn), dim3(64), 0, stream,
                     out_season, Tn + PREDn, 0, Wse, bs, spb);
  // 10. level EMA
  hipLaunchKernelGGL(lvl_kernel, dim3(1), dim3(128), 0, stream,
                     level, spb, gpb, v0_l, sw_l, out_lvl);

  (void)in_sizes; (void)n_in; (void)out_size; (void)ws_size;
}

// Round 3
// 704.525 us; speedup vs baseline: 3.2946x; 2.4702x over previous
//
#include <hip/hip_runtime.h>
#include <math.h>

// Problem constants
#define Bn 16
#define Tn 512
#define Dn 512
#define COUTn 7
#define PREDn 96

using f32x4 = __attribute__((ext_vector_type(4))) float;
using bf16x8 = __attribute__((ext_vector_type(8))) __bf16;

__device__ __forceinline__ unsigned short f2b(float f) {
  unsigned int u = __float_as_uint(f);
  u += 0x7fff + ((u >> 16) & 1);
  return (unsigned short)(u >> 16);
}

__device__ __forceinline__ void gld16(const void* g, void* l) {
  __builtin_amdgcn_global_load_lds(
      (const __attribute__((address_space(1))) void*)g,
      (__attribute__((address_space(3))) void*)l, 16, 0, 0);
}

// ---------------------------------------------------------------------------
// f32 -> bf16 conversion (n multiple of 4)
// ---------------------------------------------------------------------------
__global__ __launch_bounds__(256) void cvt_bf16(
    const float* __restrict__ in, unsigned short* __restrict__ out, int n) {
  int i = (blockIdx.x * 256 + threadIdx.x) * 4;
  if (i + 3 < n) {
    float4 v = *reinterpret_cast<const float4*>(&in[i]);
    ushort4 o;
    o.x = f2b(v.x); o.y = f2b(v.y); o.z = f2b(v.z); o.w = f2b(v.w);
    *reinterpret_cast<ushort4*>(&out[i]) = o;
  }
}

// ---------------------------------------------------------------------------
// MFMA GEMM: C[M,N] = A[M,Kd] @ W[N,Kd]^T  (bf16 in, f32 acc)
// 128x128 tile, BK=32, 256 thr (4 waves, 2x2), global_load_lds + XOR swizzle.
// MODE 0: C=acc+bias (f32).  MODE 1: Cb=bf16(relu(acc)).  MODE 2: C+=acc.
// ---------------------------------------------------------------------------
template <int MODE>
__global__ __launch_bounds__(256) void gemm_mfma(
    const unsigned short* __restrict__ A, const unsigned short* __restrict__ W,
    const float* __restrict__ bias, float* __restrict__ C,
    unsigned short* __restrict__ Cb, int M, int N, int Kd) {
  __shared__ unsigned short lA[4096];
  __shared__ unsigned short lB[4096];
  int tid = threadIdx.x;
  int wv = tid >> 6, lane = tid & 63;
  int m0 = blockIdx.y * 128, n0 = blockIdx.x * 128;
  int wr = (wv >> 1) * 64, wc = (wv & 1) * 64;

  // staging geometry: wave wv stages tile rows [wv*32, wv*32+31], 4 lanes/row
  int rA0 = wv * 32 + (lane >> 2);
  int rA1 = rA0 + 16;
  int kk = (lane & 3) * 8;
  int kk0 = kk ^ (((rA0 >> 1) & 3) << 3);   // pre-swizzled source column
  int kk1 = kk ^ (((rA1 >> 1) & 3) << 3);
  int gmA0 = m0 + rA0; if (gmA0 > M - 1) gmA0 = M - 1;
  int gmA1 = m0 + rA1; if (gmA1 > M - 1) gmA1 = M - 1;
  const unsigned short* a0 = A + (size_t)gmA0 * Kd + kk0;
  const unsigned short* a1 = A + (size_t)gmA1 * Kd + kk1;
  const unsigned short* b0 = W + (size_t)(n0 + rA0) * Kd + kk0;
  const unsigned short* b1 = W + (size_t)(n0 + rA1) * Kd + kk1;
  unsigned short* dA0 = &lA[wv * 1024];
  unsigned short* dA1 = &lA[wv * 1024 + 512];
  unsigned short* dB0 = &lB[wv * 1024];
  unsigned short* dB1 = &lB[wv * 1024 + 512];

  // fragment read offsets (swizzled to match)
  int frow = lane & 15, fk = (lane >> 4) * 8;
  int ia[4], ib[4];
#pragma unroll
  for (int i = 0; i < 4; ++i) {
    int r = wr + i * 16 + frow;
    ia[i] = r * 32 + (fk ^ (((r >> 1) & 3) << 3));
    int rb = wc + i * 16 + frow;
    ib[i] = rb * 32 + (fk ^ (((rb >> 1) & 3) << 3));
  }

  f32x4 acc[4][4] = {};

  for (int k0 = 0; k0 < Kd; k0 += 32) {
    gld16(a0 + k0, dA0);
    gld16(a1 + k0, dA1);
    gld16(b0 + k0, dB0);
    gld16(b1 + k0, dB1);
    __syncthreads();
    bf16x8 af[4], bw[4];
#pragma unroll
    for (int i = 0; i < 4; ++i) {
      af[i] = *reinterpret_cast<const bf16x8*>(&lA[ia[i]]);
      bw[i] = *reinterpret_cast<const bf16x8*>(&lB[ib[i]]);
    }
#pragma unroll
    for (int i = 0; i < 4; ++i)
#pragma unroll
      for (int j = 0; j < 4; ++j)
        acc[i][j] = __builtin_amdgcn_mfma_f32_16x16x32_bf16(
            af[i], bw[j], acc[i][j], 0, 0, 0);
    __syncthreads();
  }

  int ccol = lane & 15, crow4 = (lane >> 4) * 4;
#pragma unroll
  for (int i = 0; i < 4; ++i) {
    int gm0 = m0 + wr + i * 16 + crow4;
#pragma unroll
    for (int j = 0; j < 4; ++j) {
      int gn = n0 + wc + j * 16 + ccol;
      float bv = 0.f;
      if (MODE == 0) bv = bias[gn];
#pragma unroll
      for (int r = 0; r < 4; ++r) {
        int gm = gm0 + r;
        if (gm < M) {
          size_t o = (size_t)gm * N + gn;
          float v = acc[i][j][r] + bv;
          if (MODE == 1) Cb[o] = f2b(fmaxf(v, 0.f));
          else if (MODE == 2) C[o] += v;
          else C[o] = v;
        }
      }
    }
  }
}

// ---------------------------------------------------------------------------
// Twiddle init: twc/tws[k][t] = cos/sin(2*pi*((k*t)&511)/512) in f64,
// plus 512-entry f32 synthesis tables.
// ---------------------------------------------------------------------------
__global__ __launch_bounds__(256) void twiddle_init(
    double* __restrict__ twc, double* __restrict__ tws,
    float* __restrict__ c512, float* __restrict__ s512) {
  int idx = blockIdx.x * 256 + threadIdx.x;   // 0..131071
  int k = idx >> 9, t = idx & 511;
  int m = (k * t) & 511;
  double ang = (double)m * (M_PI / 256.0);
  twc[idx] = cos(ang);
  tws[idx] = sin(ang);
  if (idx < 512) {
    double a2 = (double)idx * (M_PI / 256.0);
    c512[idx] = (float)cos(a2);
    s512[idx] = (float)sin(a2);
  }
}

// ---------------------------------------------------------------------------
// DFT GEMM (f64 accumulate): Fre[b][k][d] =  sum_t twc[k][t]*res[b][t][d]
//                            Fim[b][k][d] = -sum_t tws[k][t]*res[b][t][d]
// ---------------------------------------------------------------------------
__global__ __launch_bounds__(256) void dft_gemm(
    const double* __restrict__ twc, const double* __restrict__ tws,
    const float* __restrict__ res,
    double* __restrict__ Fre, double* __restrict__ Fim) {
  int b = blockIdx.z;
  int k0 = blockIdx.y * 64;
  int d0 = blockIdx.x * 64;
  __shared__ double Ac[16][66];
  __shared__ double As_[16][66];
  __shared__ float Bs[16][68];
  int tid = threadIdx.x;
  int tx = tid & 15, ty = tid >> 4;
  int lr = tid >> 2;
  int lc = (tid & 3) * 4;
  int br = tid >> 4;
  int bc = (tid & 15) * 4;

  double accR[4][4] = {};
  double accI[4][4] = {};
  const float* resb = res + (size_t)b * (Tn * Dn);

  for (int t0 = 0; t0 < 512; t0 += 16) {
    const double* ac = &twc[(size_t)(k0 + lr) * 512 + t0 + lc];
    const double* as = &tws[(size_t)(k0 + lr) * 512 + t0 + lc];
    double2 c01 = *reinterpret_cast<const double2*>(ac);
    double2 c23 = *reinterpret_cast<const double2*>(ac + 2);
    double2 s01 = *reinterpret_cast<const double2*>(as);
    double2 s23 = *reinterpret_cast<const double2*>(as + 2);
    Ac[lc + 0][lr] = c01.x; Ac[lc + 1][lr] = c01.y;
    Ac[lc + 2][lr] = c23.x; Ac[lc + 3][lr] = c23.y;
    As_[lc + 0][lr] = s01.x; As_[lc + 1][lr] = s01.y;
    As_[lc + 2][lr] = s23.x; As_[lc + 3][lr] = s23.y;
    float4 bv = *reinterpret_cast<const float4*>(
        &resb[(size_t)(t0 + br) * 512 + d0 + bc]);
    *reinterpret_cast<float4*>(&Bs[br][bc]) = bv;
    __syncthreads();
#pragma unroll
    for (int kk = 0; kk < 16; ++kk) {
      double a_c[4], a_s[4], bb[4];
#pragma unroll
      for (int i = 0; i < 4; ++i) {
        a_c[i] = Ac[kk][ty * 4 + i];
        a_s[i] = As_[kk][ty * 4 + i];
      }
#pragma unroll
      for (int j = 0; j < 4; ++j) bb[j] = (double)Bs[kk][tx * 4 + j];
#pragma unroll
      for (int i = 0; i < 4; ++i)
#pragma unroll
        for (int j = 0; j < 4; ++j) {
          accR[i][j] += a_c[i] * bb[j];
          accI[i][j] -= a_s[i] * bb[j];
        }
    }
    __syncthreads();
  }
#pragma unroll
  for (int i = 0; i < 4; ++i) {
    int k = k0 + ty * 4 + i;
#pragma unroll
    for (int j = 0; j < 4; ++j) {
      int d = d0 + tx * 4 + j;
      size_t o = ((size_t)b * 256 + k) * 512 + d;
      Fre[o] = accR[i][j];
      Fim[o] = accI[i][j];
    }
  }
}

// ---------------------------------------------------------------------------
// Top-16 per column (one wave per (b,d)).
// ---------------------------------------------------------------------------
__global__ __launch_bounds__(64) void topk_kernel(
    const double* __restrict__ Fre, const double* __restrict__ Fim,
    int* __restrict__ kidx, float* __restrict__ cjb, float* __restrict__ sjb) {
  int blk = blockIdx.x;
  int b = blk >> 9;
  int d = blk & 511;
  int lane = threadIdx.x;

  double re[4], im[4], m2[4];
#pragma unroll
  for (int i = 0; i < 4; ++i) {
    int k = 1 + lane + 64 * i;
    if (k <= 255) {
      size_t o = ((size_t)b * 256 + k) * 512 + d;
      re[i] = Fre[o];
      im[i] = Fim[o];
      m2[i] = re[i] * re[i] + im[i] * im[i];
    } else {
      re[i] = 0.0; im[i] = 0.0; m2[i] = -1.0;
    }
  }

  for (int j = 0; j < 16; ++j) {
    double bm = -2.0; int bk = 1 << 20;
#pragma unroll
    for (int i = 0; i < 4; ++i) {
      int k = 1 + lane + 64 * i;
      if (m2[i] > bm || (m2[i] == bm && k < bk)) { bm = m2[i]; bk = k; }
    }
    for (int o = 32; o > 0; o >>= 1) {
      double om = __shfl_down(bm, o, 64);
      int ok = __shfl_down(bk, o, 64);
      if (om > bm || (om == bm && ok < bk)) { bm = om; bk = ok; }
    }
    bk = __shfl(bk, 0, 64);
#pragma unroll
    for (int i = 0; i < 4; ++i) {
      int k = 1 + lane + 64 * i;
      if (k == bk) {
        size_t o = ((size_t)b * 16 + j) * 512 + d;
        kidx[o] = k;
        cjb[o] = (float)(re[i] * (2.0 / 512.0));
        sjb[o] = (float)(im[i] * (2.0 / 512.0));
        m2[i] = -1.0;
      }
    }
  }
}

// ---------------------------------------------------------------------------
// Synthesis: season (f32) + res1 (bf16) fused.
// ---------------------------------------------------------------------------
__global__ __launch_bounds__(512) void synth_kernel(
    const int* __restrict__ kidx, const float* __restrict__ cjb,
    const float* __restrict__ sjb, const float* __restrict__ c512,
    const float* __restrict__ s512, const float* __restrict__ res,
    float* __restrict__ season, unsigned short* __restrict__ res1b) {
  int b = blockIdx.y;
  int t0 = blockIdx.x * 16;
  int d = threadIdx.x;

  __shared__ float ct[512], st[512];
  ct[d] = c512[d];
  st[d] = s512[d];
  __syncthreads();

  int kk[16];
  float cw[16], sw[16];
#pragma unroll
  for (int j = 0; j < 16; ++j) {
    size_t o = ((size_t)b * 16 + j) * 512 + d;
    kk[j] = kidx[o];
    cw[j] = cjb[o];
    sw[j] = sjb[o];
  }

  for (int tt = 0; tt < 16; ++tt) {
    int t = t0 + tt;
    float acc = 0.f;
#pragma unroll
    for (int j = 0; j < 16; ++j) {
      int m = (kk[j] * t) & 511;
      acc += cw[j] * ct[m] - sw[j] * st[m];
    }
    season[((size_t)(b * (Tn + PREDn) + t)) * 512 + d] = acc;
    if (t < Tn) {
      size_t o = ((size_t)(b * Tn + t)) * 512 + d;
      res1b[o] = f2b(res[o] - acc);
    }
  }
}

// ---------------------------------------------------------------------------
// growth EMA: reads v (f32), writes gr rows (bf16): row0=v0_g, row t+1=state
// ---------------------------------------------------------------------------
__global__ __launch_bounds__(256) void ema_growth_kernel(
    const float* __restrict__ v, const float* __restrict__ z0,
    const float* __restrict__ v0_g, const float* __restrict__ sw_g,
    unsigned short* __restrict__ grb) {
  int gid = blockIdx.x * 256 + threadIdx.x;   // 0..8191
  int b = gid >> 9;
  int hd = gid & 511;
  int h = hd >> 6;
  float alpha = 1.0f / (1.0f + expf(-sw_g[h]));
  float one_m = 1.0f - alpha;
  float prev = z0[hd];
  float s = v0_g[hd];
  grb[((size_t)(b * (Tn + 1))) * 512 + hd] = f2b(s);
  for (int t = 0; t < Tn; ++t) {
    float cur = v[((size_t)(b * Tn + t)) * 512 + hd];
    float df = cur - prev;
    prev = cur;
    s = alpha * s + one_m * df;
    grb[((size_t)(b * (Tn + 1) + t + 1)) * 512 + hd] = f2b(s);
  }
}

// ---------------------------------------------------------------------------
// LN0: val = res - season - growth ; writes h1 (f32) + h1b (bf16)
// ---------------------------------------------------------------------------
__global__ __launch_bounds__(256) void ln0_kernel(
    const float* __restrict__ res, const float* __restrict__ season,
    const float* __restrict__ growth, const float* __restrict__ g,
    const float* __restrict__ bvec, float* __restrict__ h1,
    unsigned short* __restrict__ h1b) {
  int row = blockIdx.x, b = row >> 9, t = row & 511;
  int tid = threadIdx.x;
  const float* xr = res + (size_t)row * 512;
  const float* sr = season + ((size_t)(b * (Tn + PREDn) + t)) * 512;
  const float* gr = growth + ((size_t)(b * (Tn + 1) + t + 1)) * 512;
  float2 xv = *reinterpret_cast<const float2*>(&xr[tid * 2]);
  float2 sv = *reinterpret_cast<const float2*>(&sr[tid * 2]);
  float2 gv2 = *reinterpret_cast<const float2*>(&gr[tid * 2]);
  float v0 = xv.x - sv.x - gv2.x;
  float v1 = xv.y - sv.y - gv2.y;
  float s1 = v0 + v1;
  float s2 = v0 * v0 + v1 * v1;
  for (int o = 32; o > 0; o >>= 1) {
    s1 += __shfl_down(s1, o, 64);
    s2 += __shfl_down(s2, o, 64);
  }
  __shared__ float r1[4], r2[4];
  __shared__ float mu_s, rstd_s;
  int wv = tid >> 6, ln = tid & 63;
  if (ln == 0) { r1[wv] = s1; r2[wv] = s2; }
  __syncthreads();
  if (tid == 0) {
    float S1 = r1[0] + r1[1] + r1[2] + r1[3];
    float S2 = r2[0] + r2[1] + r2[2] + r2[3];
    float mu = S1 * (1.0f / 512.0f);
    float var = S2 * (1.0f / 512.0f) - mu * mu;
    mu_s = mu;
    rstd_s = rsqrtf(var + 1e-5f);
  }
  __syncthreads();
  float mu = mu_s, rstd = rstd_s;
  float2 gv = *reinterpret_cast<const float2*>(&g[tid * 2]);
  float2 bv = *reinterpret_cast<const float2*>(&bvec[tid * 2]);
  float o0 = (v0 - mu) * rstd * gv.x + bv.x;
  float o1 = (v1 - mu) * rstd * gv.y + bv.y;
  size_t o = (size_t)row * 512 + tid * 2;
  *reinterpret_cast<float2*>(&h1[o]) = make_float2(o0, o1);
  ushort2 hb; hb.x = f2b(o0); hb.y = f2b(o1);
  *reinterpret_cast<ushort2*>(&h1b[o]) = hb;
}

// ---------------------------------------------------------------------------
// LN1: X already holds h1+ff (in-place). out = LN(X)*g + b
// ---------------------------------------------------------------------------
__global__ __launch_bounds__(256) void ln1_kernel(
    const float* __restrict__ X, const float* __restrict__ g,
    const float* __restrict__ bvec, float* __restrict__ out) {
  int row = blockIdx.x;
  int tid = threadIdx.x;
  const float* xr = X + (size_t)row * 512;
  float2 xv = *reinterpret_cast<const float2*>(&xr[tid * 2]);
  float v0 = xv.x, v1 = xv.y;
  float s1 = v0 + v1;
  float s2 = v0 * v0 + v1 * v1;
  for (int o = 32; o > 0; o >>= 1) {
    s1 += __shfl_down(s1, o, 64);
    s2 += __shfl_down(s2, o, 64);
  }
  __shared__ float r1[4], r2[4];
  __shared__ float mu_s, rstd_s;
  int wv = tid >> 6, ln = tid & 63;
  if (ln == 0) { r1[wv] = s1; r2[wv] = s2; }
  __syncthreads();
  if (tid == 0) {
    float S1 = r1[0] + r1[1] + r1[2] + r1[3];
    float S2 = r2[0] + r2[1] + r2[2] + r2[3];
    float mu = S1 * (1.0f / 512.0f);
    float var = S2 * (1.0f / 512.0f) - mu * mu;
    mu_s = mu;
    rstd_s = rsqrtf(var + 1e-5f);
  }
  __syncthreads();
  float mu = mu_s, rstd = rstd_s;
  float2 gv = *reinterpret_cast<const float2*>(&g[tid * 2]);
  float2 bv = *reinterpret_cast<const float2*>(&bvec[tid * 2]);
  float o0 = (v0 - mu) * rstd * gv.x + bv.x;
  float o1 = (v1 - mu) * rstd * gv.y + bv.y;
  *reinterpret_cast<float2*>(&out[(size_t)row * 512 + tid * 2]) =
      make_float2(o0, o1);
}

// ---------------------------------------------------------------------------
// 7-wide projection
// ---------------------------------------------------------------------------
__global__ __launch_bounds__(64) void proj7_kernel(
    const float* __restrict__ X, int strB, int off,
    const float* __restrict__ Wc, const float* __restrict__ bc,
    float* __restrict__ outp) {
  int bt = blockIdx.x;
  int b = bt >> 9;
  int t = bt & 511;
  int lane = threadIdx.x;
  const float* row = X + ((size_t)(b * strB + off + t)) * 512;
  float x[8];
#pragma unroll
  for (int i = 0; i < 8; ++i) x[i] = row[lane + 64 * i];
#pragma unroll
  for (int c = 0; c < 7; ++c) {
    float s = 0.f;
#pragma unroll
    for (int i = 0; i < 8; ++i) s += x[i] * Wc[c * 512 + lane + 64 * i];
    for (int o = 32; o > 0; o >>= 1) s += __shfl_down(s, o, 64);
    if (lane == 0) outp[((size_t)bt) * 7 + c] = s + bc[c];
  }
}

// ---------------------------------------------------------------------------
// level EMA with aux
// ---------------------------------------------------------------------------
__global__ __launch_bounds__(128) void lvl_kernel(
    const float* __restrict__ level, const float* __restrict__ sp,
    const float* __restrict__ gp, const float* __restrict__ v0_l,
    const float* __restrict__ sw_l, float* __restrict__ out_lvl) {
  int tid = blockIdx.x * 128 + threadIdx.x;
  if (tid >= Bn * COUTn) return;
  int b = tid / COUTn;
  int c = tid % COUTn;
  float alpha = 1.0f / (1.0f + expf(-sw_l[c]));
  float one_m = 1.0f - alpha;
  float s = v0_l[c];
  for (int t = 0; t < Tn; ++t) {
    size_t i = ((size_t)(b * Tn + t)) * COUTn + c;
    float esv = level[i] - sp[i];
    s = alpha * s + one_m * esv + alpha * gp[i];
    out_lvl[i] = s;
  }
}

// ---------------------------------------------------------------------------
extern "C" void kernel_launch(void* const* d_in, const int* in_sizes, int n_in,
                              void* d_out, int out_size, void* d_ws,
                              size_t ws_size, hipStream_t stream) {
  const float* res = (const float*)d_in[0];
  const float* level = (const float*)d_in[1];
  const float* Wi = (const float*)d_in[2];
  const float* bi = (const float*)d_in[3];
  const float* z0 = (const float*)d_in[4];
  const float* v0_g = (const float*)d_in[5];
  const float* sw_g = (const float*)d_in[6];
  const float* Wo = (const float*)d_in[7];
  const float* bo = (const float*)d_in[8];
  const float* W1 = (const float*)d_in[9];
  const float* W2 = (const float*)d_in[10];
  const float* g1 = (const float*)d_in[11];
  const float* b1 = (const float*)d_in[12];
  const float* g2 = (const float*)d_in[13];
  const float* b2 = (const float*)d_in[14];
  const float* Wg = (const float*)d_in[15];
  const float* bg = (const float*)d_in[16];
  const float* Wse = (const float*)d_in[17];
  const float* bs = (const float*)d_in[18];
  const float* v0_l = (const float*)d_in[19];
  const float* sw_l = (const float*)d_in[20];

  float* out = (float*)d_out;
  float* out_h = out;                               // 16*512*512
  float* out_lvl = out + 4194304;                   // 16*512*7
  float* out_growth = out + 4251648;                // 16*513*512
  float* out_season = out + 8454144;                // 16*608*512

  float* wsf = (float*)d_ws;
  // Slot A [0 .. 2,097,152): res1_b -> h1_b -> gpb/spb
  unsigned short* res1_b = (unsigned short*)wsf;
  unsigned short* h1_b = (unsigned short*)wsf;
  float* gpb = wsf;
  float* spb = wsf + 57344;
  // Slot B [2,097,152 .. 10,485,760): Fre/Fim -> vbuf/grbuf_b -> ff1_b
  double* Fre = (double*)(wsf + 2097152);
  double* Fim = (double*)(wsf + 6291456);
  float* vbuf = wsf + 2097152;
  unsigned short* grbuf_b = (unsigned short*)(wsf + 6291456);
  unsigned short* ff1_b = (unsigned short*)(wsf + 2097152);
  // Slot C [10,485,760 .. 14,680,064): twiddles/topk scratch -> h1 (f32)
  double* twc = (double*)(wsf + 10485760);
  double* tws = (double*)(wsf + 10747904);
  float* c512 = wsf + 11010048;
  float* s512 = wsf + 11010560;
  int* kidx = (int*)(wsf + 11011072);
  float* cjb = wsf + 11142144;
  float* sjb = wsf + 11273216;
  float* h1 = wsf + 10485760;
  // Slot D [14,680,064 .. 15,990,784): bf16 weights (all phases)
  unsigned short* Wi_b = (unsigned short*)(wsf + 14680064);
  unsigned short* Wo_b = (unsigned short*)(wsf + 14811136);
  unsigned short* W1_b = (unsigned short*)(wsf + 14942208);
  unsigned short* W2_b = (unsigned short*)(wsf + 15466496);

  // 0. weight conversions
  hipLaunchKernelGGL(cvt_bf16, dim3(256), dim3(256), 0, stream, Wi, Wi_b, 262144);
  hipLaunchKernelGGL(cvt_bf16, dim3(256), dim3(256), 0, stream, Wo, Wo_b, 262144);
  hipLaunchKernelGGL(cvt_bf16, dim3(1024), dim3(256), 0, stream, W1, W1_b, 1048576);
  hipLaunchKernelGGL(cvt_bf16, dim3(1024), dim3(256), 0, stream, W2, W2_b, 1048576);

  // 1. season: twiddle -> DFT gemm -> topk -> synthesis (+res1_b fused)
  hipLaunchKernelGGL(twiddle_init, dim3(512), dim3(256), 0, stream,
                     twc, tws, c512, s512);
  hipLaunchKernelGGL(dft_gemm, dim3(8, 4, 16), dim3(256), 0, stream,
                     twc, tws, res, Fre, Fim);
  hipLaunchKernelGGL(topk_kernel, dim3(Bn * Dn), dim3(64), 0, stream,
                     Fre, Fim, kidx, cjb, sjb);
  hipLaunchKernelGGL(synth_kernel, dim3(38, 16), dim3(512), 0, stream,
                     kidx, cjb, sjb, c512, s512, res, out_season, res1_b);
  // 3. v = res1 @ Wi^T + bi
  hipLaunchKernelGGL((gemm_mfma<0>), dim3(4, 64), dim3(256), 0, stream,
                     res1_b, Wi_b, bi, vbuf, (unsigned short*)nullptr,
                     8192, 512, 512);
  // 4. growth EMA -> grbuf_b (bf16)
  hipLaunchKernelGGL(ema_growth_kernel, dim3(32), dim3(256), 0, stream,
                     vbuf, z0, v0_g, sw_g, grbuf_b);
  // 5. growth = gr @ Wo^T + bo  (direct to output, M=8208)
  hipLaunchKernelGGL((gemm_mfma<0>), dim3(4, 65), dim3(256), 0, stream,
                     grbuf_b, Wo_b, bo, out_growth, (unsigned short*)nullptr,
                     8208, 512, 512);
  // 6. h1 = LN(res - season - growth), + bf16 copy
  hipLaunchKernelGGL(ln0_kernel, dim3(Bn * Tn), dim3(256), 0, stream,
                     res, out_season, out_growth, g1, b1, h1, h1_b);
  // 7. ff1 = relu(h1 @ W1^T) -> bf16
  hipLaunchKernelGGL((gemm_mfma<1>), dim3(16, 64), dim3(256), 0, stream,
                     h1_b, W1_b, (const float*)nullptr, (float*)nullptr, ff1_b,
                     8192, 2048, 512);
  // 8. h1 += ff1 @ W2^T (in place)
  hipLaunchKernelGGL((gemm_mfma<2>), dim3(4, 64), dim3(256), 0, stream,
                     ff1_b, W2_b, (const float*)nullptr, h1,
                     (unsigned short*)nullptr, 8192, 512, 2048);
  // 9. h = LN(h1)
  hipLaunchKernelGGL(ln1_kernel, dim3(Bn * Tn), dim3(256), 0, stream,
                     h1, g2, b2, out_h);
  // 10. gp / sp projections
  hipLaunchKernelGGL(proj7_kernel, dim3(Bn * Tn), dim3(64), 0, stream,
                     out_growth, Tn + 1, 1, Wg, bg, gpb);
  hipLaunchKernelGGL(proj7_kernel, dim3(Bn * Tn), dim3(64), 0, stream,
                     out_season, Tn + PREDn, 0, Wse, bs, spb);
  // 11. level EMA
  hipLaunchKernelGGL(lvl_kernel, dim3(1), dim3(128), 0, stream,
                     level, spb, gpb, v0_l, sw_l, out_lvl);

  (void)in_sizes; (void)n_in; (void)out_size; (void)ws_size;
}

// Round 5
// 506.433 us; speedup vs baseline: 4.5832x; 1.3912x over previous
//
#include <hip/hip_runtime.h>
#include <math.h>

// Problem constants
#define Bn 16
#define Tn 512
#define Dn 512
#define COUTn 7
#define PREDn 96

using f32x4 = __attribute__((ext_vector_type(4))) float;
using bf16x8 = __attribute__((ext_vector_type(8))) __bf16;

__device__ __forceinline__ unsigned short f2b(float f) {
  unsigned int u = __float_as_uint(f);
  u += 0x7fff + ((u >> 16) & 1);
  return (unsigned short)(u >> 16);
}

__device__ __forceinline__ void gld16(const void* g, void* l) {
  __builtin_amdgcn_global_load_lds(
      (const __attribute__((address_space(1))) void*)g,
      (__attribute__((address_space(3))) void*)l, 16, 0, 0);
}

// ---------------------------------------------------------------------------
// f32 -> bf16 conversion (n multiple of 4)
// ---------------------------------------------------------------------------
__global__ __launch_bounds__(256) void cvt_bf16(
    const float* __restrict__ in, unsigned short* __restrict__ out, int n) {
  int i = (blockIdx.x * 256 + threadIdx.x) * 4;
  if (i + 3 < n) {
    float4 v = *reinterpret_cast<const float4*>(&in[i]);
    ushort4 o;
    o.x = f2b(v.x); o.y = f2b(v.y); o.z = f2b(v.z); o.w = f2b(v.w);
    *reinterpret_cast<ushort4*>(&out[i]) = o;
  }
}

// ---------------------------------------------------------------------------
// Twiddle init: bf16 screen tables twc_b/tws_b[k][t] (k,t<512 table values),
// f64 rotation table tabw[k]=(cos, -sin)(2pi k/512), f32 synth tables.
// ---------------------------------------------------------------------------
__global__ __launch_bounds__(256) void twiddle_init2(
    unsigned short* __restrict__ twc_b, unsigned short* __restrict__ tws_b,
    double* __restrict__ tabw, float* __restrict__ c512,
    float* __restrict__ s512) {
  int idx = blockIdx.x * 256 + threadIdx.x;   // 0..131071
  int k = idx >> 9, t = idx & 511;
  int m = (k * t) & 511;
  double ang = (double)m * (M_PI / 256.0);
  twc_b[idx] = f2b((float)cos(ang));
  tws_b[idx] = f2b((float)sin(ang));
  if (idx < 512) {
    double a2 = (double)idx * (M_PI / 256.0);
    c512[idx] = (float)cos(a2);
    s512[idx] = (float)sin(a2);
    tabw[2 * idx] = cos(a2);
    tabw[2 * idx + 1] = -sin(a2);
  }
}

// ---------------------------------------------------------------------------
// Transpose + cvt: resT[b][d][t] = bf16(res[b][t][d])
// ---------------------------------------------------------------------------
__global__ __launch_bounds__(256) void transpose_cvt(
    const float* __restrict__ res, unsigned short* __restrict__ resT) {
  __shared__ unsigned short tile[64][65];
  int b = blockIdx.z;
  int t0 = blockIdx.y * 64, d0 = blockIdx.x * 64;
  int tid = threadIdx.x;
  int c = tid & 63, r4 = (tid >> 6) * 16;
#pragma unroll
  for (int i = 0; i < 16; ++i) {
    int t = t0 + r4 + i;
    tile[r4 + i][c] = f2b(res[((size_t)(b * 512 + t)) * 512 + d0 + c]);
  }
  __syncthreads();
#pragma unroll
  for (int i = 0; i < 16; ++i) {
    int d = d0 + r4 + i;
    resT[((size_t)(b * 512 + d)) * 512 + t0 + c] = tile[c][r4 + i];
  }
}

// ---------------------------------------------------------------------------
// Screen: mag[b][k][d] ~= |X_k(b,d)|^2 via bf16 MFMA.
// Block tile: 64 k x 128 d, K(t)=512 in steps of 32. 4 waves (1x4 over d).
// ---------------------------------------------------------------------------
__global__ __launch_bounds__(256) void screen_mfma(
    const unsigned short* __restrict__ twc_b,
    const unsigned short* __restrict__ tws_b,
    const unsigned short* __restrict__ resT, float* __restrict__ mag) {
  __shared__ unsigned short lAc[2048];   // 64 x 32
  __shared__ unsigned short lAs[2048];   // 64 x 32
  __shared__ unsigned short lB[4096];    // 128 x 32
  int tid = threadIdx.x;
  int wv = tid >> 6, lane = tid & 63;
  int b = blockIdx.z;
  int k0 = blockIdx.y * 64;
  int d0 = blockIdx.x * 128;

  int rA = wv * 16 + (lane >> 2);
  int rB0 = wv * 32 + (lane >> 2);
  int rB1 = rB0 + 16;
  int kk = (lane & 3) * 8;
  int kkA = kk ^ (((rA >> 1) & 3) << 3);
  int kkB0 = kk ^ (((rB0 >> 1) & 3) << 3);
  int kkB1 = kk ^ (((rB1 >> 1) & 3) << 3);
  const unsigned short* ac = twc_b + (size_t)(k0 + rA) * 512 + kkA;
  const unsigned short* as = tws_b + (size_t)(k0 + rA) * 512 + kkA;
  const unsigned short* bb0 = resT + ((size_t)(b * 512 + d0 + rB0)) * 512 + kkB0;
  const unsigned short* bb1 = resT + ((size_t)(b * 512 + d0 + rB1)) * 512 + kkB1;
  unsigned short* dAc = &lAc[wv * 512];
  unsigned short* dAs = &lAs[wv * 512];
  unsigned short* dB0 = &lB[wv * 1024];
  unsigned short* dB1 = &lB[wv * 1024 + 512];

  int frow = lane & 15, fk = (lane >> 4) * 8;
  int ia[4], ib[2];
#pragma unroll
  for (int i = 0; i < 4; ++i) {
    int r = i * 16 + frow;
    ia[i] = r * 32 + (fk ^ (((r >> 1) & 3) << 3));
  }
#pragma unroll
  for (int j = 0; j < 2; ++j) {
    int r = wv * 32 + j * 16 + frow;
    ib[j] = r * 32 + (fk ^ (((r >> 1) & 3) << 3));
  }

  f32x4 accR[4][2] = {};
  f32x4 accI[4][2] = {};
  for (int t0 = 0; t0 < 512; t0 += 32) {
    gld16(ac + t0, dAc);
    gld16(as + t0, dAs);
    gld16(bb0 + t0, dB0);
    gld16(bb1 + t0, dB1);
    __syncthreads();
    bf16x8 afc[4], afs[4], bw[2];
#pragma unroll
    for (int i = 0; i < 4; ++i) {
      afc[i] = *reinterpret_cast<const bf16x8*>(&lAc[ia[i]]);
      afs[i] = *reinterpret_cast<const bf16x8*>(&lAs[ia[i]]);
    }
#pragma unroll
    for (int j = 0; j < 2; ++j)
      bw[j] = *reinterpret_cast<const bf16x8*>(&lB[ib[j]]);
#pragma unroll
    for (int i = 0; i < 4; ++i)
#pragma unroll
      for (int j = 0; j < 2; ++j) {
        accR[i][j] = __builtin_amdgcn_mfma_f32_16x16x32_bf16(
            afc[i], bw[j], accR[i][j], 0, 0, 0);
        accI[i][j] = __builtin_amdgcn_mfma_f32_16x16x32_bf16(
            afs[i], bw[j], accI[i][j], 0, 0, 0);
      }
    __syncthreads();
  }

  int ccol = lane & 15, crow4 = (lane >> 4) * 4;
#pragma unroll
  for (int i = 0; i < 4; ++i) {
    int kb = k0 + i * 16 + crow4;
#pragma unroll
    for (int j = 0; j < 2; ++j) {
      int d = d0 + wv * 32 + j * 16 + ccol;
#pragma unroll
      for (int r = 0; r < 4; ++r) {
        float re = accR[i][j][r], im = accI[i][j][r];
        mag[((size_t)(b * 256 + kb + r)) * 512 + d] = re * re + im * im;
      }
    }
  }
}

// ---------------------------------------------------------------------------
// Candidate top-32 per column from screened mags (one wave per (b,d)).
// ---------------------------------------------------------------------------
__global__ __launch_bounds__(64) void cand32(
    const float* __restrict__ mag, int* __restrict__ cand) {
  int blk = blockIdx.x;   // 0..8191
  int b = blk >> 9;
  int d = blk & 511;
  int lane = threadIdx.x;
  float m2[4];
#pragma unroll
  for (int i = 0; i < 4; ++i) {
    int k = 1 + lane + 64 * i;
    m2[i] = (k <= 255) ? mag[((size_t)(b * 256 + k)) * 512 + d] : -1.f;
  }
  for (int j = 0; j < 32; ++j) {
    float bm = -2.f; int bk = 1 << 20;
#pragma unroll
    for (int i = 0; i < 4; ++i) {
      int k = 1 + lane + 64 * i;
      if (m2[i] > bm || (m2[i] == bm && k < bk)) { bm = m2[i]; bk = k; }
    }
    for (int o = 32; o > 0; o >>= 1) {
      float om = __shfl_down(bm, o, 64);
      int ok = __shfl_down(bk, o, 64);
      if (om > bm || (om == bm && ok < bk)) { bm = om; bk = ok; }
    }
    bk = __shfl(bk, 0, 64);
    if (lane == 0) cand[((size_t)(b * 32 + j)) * 512 + d] = bk;
#pragma unroll
    for (int i = 0; i < 4; ++i) {
      int k = 1 + lane + 64 * i;
      if (k == bk) m2[i] = -1.f;
    }
  }
}

// ---------------------------------------------------------------------------
// Refine: exact f64 DFT of 32 candidate bins per column via rotation
// recurrence; in-block exact top-16 (mag desc, k asc); writes kidx/cjb/sjb.
// Block: 16 columns x 32 bins = 512 threads, tid = bin + 32*col.
// ---------------------------------------------------------------------------
__global__ __launch_bounds__(512) void refine32(
    const float* __restrict__ res, const int* __restrict__ cand,
    const double* __restrict__ tabw, int* __restrict__ kidx,
    float* __restrict__ cjb, float* __restrict__ sjb) {
  int b = blockIdx.y;
  int d0 = blockIdx.x * 16;
  int tid = threadIdx.x;
  __shared__ float colbuf[512][17];
  for (int idx = tid; idx < 8192; idx += 512) {
    int t = idx >> 4, c = idx & 15;
    colbuf[t][c] = res[((size_t)(b * 512 + t)) * 512 + d0 + c];
  }
  __syncthreads();

  int j = tid & 31, c = tid >> 5;
  int k = cand[((size_t)(b * 32 + j)) * 512 + d0 + c];
  double wr = tabw[2 * k], wi = tabw[2 * k + 1];
  double zr = 1.0, zi = 0.0, ar = 0.0, ai = 0.0;
#pragma unroll 4
  for (int t = 0; t < 512; ++t) {
    double x = (double)colbuf[t][c];
    ar = fma(x, zr, ar);
    ai = fma(x, zi, ai);
    double nzr = fma(zr, wr, -zi * wi);
    double nzi = fma(zr, wi, zi * wr);
    zr = nzr; zi = nzi;
  }
  double m2 = ar * ar + ai * ai;
  float cjv = (float)(ar * (2.0 / 512.0));
  float sjv = (float)(ai * (2.0 / 512.0));
  for (int jo = 0; jo < 16; ++jo) {
    double bm = m2; int bk = k;
#pragma unroll
    for (int o = 16; o > 0; o >>= 1) {
      double om = __shfl_xor(bm, o, 32);
      int ok = __shfl_xor(bk, o, 32);
      if (om > bm || (om == bm && ok < bk)) { bm = om; bk = ok; }
    }
    if (k == bk) {
      size_t o = ((size_t)(b * 16 + jo)) * 512 + d0 + c;
      kidx[o] = k; cjb[o] = cjv; sjb[o] = sjv;
      m2 = -1.0;
    }
  }
}

// ---------------------------------------------------------------------------
// Synthesis: season (f32) + res1 (bf16) fused.
// ---------------------------------------------------------------------------
__global__ __launch_bounds__(512) void synth_kernel(
    const int* __restrict__ kidx, const float* __restrict__ cjb,
    const float* __restrict__ sjb, const float* __restrict__ c512,
    const float* __restrict__ s512, const float* __restrict__ res,
    float* __restrict__ season, unsigned short* __restrict__ res1b) {
  int b = blockIdx.y;
  int t0 = blockIdx.x * 16;
  int d = threadIdx.x;

  __shared__ float ct[512], st[512];
  ct[d] = c512[d];
  st[d] = s512[d];
  __syncthreads();

  int kk[16];
  float cw[16], sw[16];
#pragma unroll
  for (int j = 0; j < 16; ++j) {
    size_t o = ((size_t)(b * 16 + j)) * 512 + d;
    kk[j] = kidx[o];
    cw[j] = cjb[o];
    sw[j] = sjb[o];
  }

  for (int tt = 0; tt < 16; ++tt) {
    int t = t0 + tt;
    if (t >= Tn + PREDn) break;
    float acc = 0.f;
#pragma unroll
    for (int j = 0; j < 16; ++j) {
      int m = (kk[j] * t) & 511;
      acc += cw[j] * ct[m] - sw[j] * st[m];
    }
    season[((size_t)(b * (Tn + PREDn) + t)) * 512 + d] = acc;
    if (t < Tn) {
      size_t o = ((size_t)(b * Tn + t)) * 512 + d;
      res1b[o] = f2b(res[o] - acc);
    }
  }
}

// ---------------------------------------------------------------------------
// MFMA GEMM: C[M,N] = A[M,Kd] @ W[N,Kd]^T  (bf16 in, f32 acc)
// MODE 0: C=acc+bias (f32).  MODE 1: Cb=bf16(relu(acc)).  MODE 2: C+=acc.
// ---------------------------------------------------------------------------
template <int MODE>
__global__ __launch_bounds__(256) void gemm_mfma(
    const unsigned short* __restrict__ A, const unsigned short* __restrict__ W,
    const float* __restrict__ bias, float* __restrict__ C,
    unsigned short* __restrict__ Cb, int M, int N, int Kd) {
  __shared__ unsigned short lA[4096];
  __shared__ unsigned short lB[4096];
  int tid = threadIdx.x;
  int wv = tid >> 6, lane = tid & 63;
  int m0 = blockIdx.y * 128, n0 = blockIdx.x * 128;
  int wr = (wv >> 1) * 64, wc = (wv & 1) * 64;

  int rA0 = wv * 32 + (lane >> 2);
  int rA1 = rA0 + 16;
  int kk = (lane & 3) * 8;
  int kk0 = kk ^ (((rA0 >> 1) & 3) << 3);
  int kk1 = kk ^ (((rA1 >> 1) & 3) << 3);
  int gmA0 = m0 + rA0; if (gmA0 > M - 1) gmA0 = M - 1;
  int gmA1 = m0 + rA1; if (gmA1 > M - 1) gmA1 = M - 1;
  const unsigned short* a0 = A + (size_t)gmA0 * Kd + kk0;
  const unsigned short* a1 = A + (size_t)gmA1 * Kd + kk1;
  const unsigned short* b0 = W + (size_t)(n0 + rA0) * Kd + kk0;
  const unsigned short* b1 = W + (size_t)(n0 + rA1) * Kd + kk1;
  unsigned short* dA0 = &lA[wv * 1024];
  unsigned short* dA1 = &lA[wv * 1024 + 512];
  unsigned short* dB0 = &lB[wv * 1024];
  unsigned short* dB1 = &lB[wv * 1024 + 512];

  int frow = lane & 15, fk = (lane >> 4) * 8;
  int ia[4], ib[4];
#pragma unroll
  for (int i = 0; i < 4; ++i) {
    int r = wr + i * 16 + frow;
    ia[i] = r * 32 + (fk ^ (((r >> 1) & 3) << 3));
    int rb = wc + i * 16 + frow;
    ib[i] = rb * 32 + (fk ^ (((rb >> 1) & 3) << 3));
  }

  f32x4 acc[4][4] = {};

  for (int k0 = 0; k0 < Kd; k0 += 32) {
    gld16(a0 + k0, dA0);
    gld16(a1 + k0, dA1);
    gld16(b0 + k0, dB0);
    gld16(b1 + k0, dB1);
    __syncthreads();
    bf16x8 af[4], bw[4];
#pragma unroll
    for (int i = 0; i < 4; ++i) {
      af[i] = *reinterpret_cast<const bf16x8*>(&lA[ia[i]]);
      bw[i] = *reinterpret_cast<const bf16x8*>(&lB[ib[i]]);
    }
#pragma unroll
    for (int i = 0; i < 4; ++i)
#pragma unroll
      for (int j = 0; j < 4; ++j)
        acc[i][j] = __builtin_amdgcn_mfma_f32_16x16x32_bf16(
            af[i], bw[j], acc[i][j], 0, 0, 0);
    __syncthreads();
  }

  int ccol = lane & 15, crow4 = (lane >> 4) * 4;
#pragma unroll
  for (int i = 0; i < 4; ++i) {
    int gm0 = m0 + wr + i * 16 + crow4;
#pragma unroll
    for (int j = 0; j < 4; ++j) {
      int gn = n0 + wc + j * 16 + ccol;
      float bv = 0.f;
      if (MODE == 0) bv = bias[gn];
#pragma unroll
      for (int r = 0; r < 4; ++r) {
        int gm = gm0 + r;
        if (gm < M) {
          size_t o = (size_t)gm * N + gn;
          float v = acc[i][j][r] + bv;
          if (MODE == 1) Cb[o] = f2b(fmaxf(v, 0.f));
          else if (MODE == 2) C[o] += v;
          else C[o] = v;
        }
      }
    }
  }
}

// ---------------------------------------------------------------------------
// growth EMA, 3-phase chunked scan. Chunks of 64 over t (8 chunks).
// ---------------------------------------------------------------------------
__global__ __launch_bounds__(256) void ema_gA(
    const float* __restrict__ v, const float* __restrict__ z0,
    const float* __restrict__ sw_g, float* __restrict__ tmp,
    float* __restrict__ sumend) {
  int g = blockIdx.x * 256 + threadIdx.x;   // 65536
  int hd = g & 511;
  int ch = (g >> 9) & 7;
  int b = g >> 12;
  int h = hd >> 6;
  float alpha = 1.f / (1.f + expf(-sw_g[h]));
  float om = 1.f - alpha;
  int t0 = ch * 64;
  float prev = (t0 == 0) ? z0[hd] : v[((size_t)(b * 512 + t0 - 1)) * 512 + hd];
  float s = 0.f;
  for (int i = 0; i < 64; ++i) {
    float cur = v[((size_t)(b * 512 + t0 + i)) * 512 + hd];
    s = alpha * s + om * (cur - prev);
    prev = cur;
    tmp[((size_t)(b * 512 + t0 + i)) * 512 + hd] = s;
  }
  sumend[((size_t)(b * 512 + hd)) * 8 + ch] = s;
}

__global__ __launch_bounds__(256) void ema_gB(
    const float* __restrict__ sumend, const float* __restrict__ v0_g,
    const float* __restrict__ sw_g, float* __restrict__ carry,
    unsigned short* __restrict__ grb) {
  int g = blockIdx.x * 256 + threadIdx.x;   // 8192
  int hd = g & 511, b = g >> 9, h = hd >> 6;
  float alpha = 1.f / (1.f + expf(-sw_g[h]));
  float A64 = exp2f(64.f * log2f(alpha));
  float cin = v0_g[hd];
  grb[((size_t)(b * 513)) * 512 + hd] = f2b(cin);
  for (int ch = 0; ch < 8; ++ch) {
    carry[((size_t)(b * 512 + hd)) * 8 + ch] = cin;
    cin = A64 * cin + sumend[((size_t)(b * 512 + hd)) * 8 + ch];
  }
}

__global__ __launch_bounds__(256) void ema_gC(
    const float* __restrict__ tmp, const float* __restrict__ carry,
    const float* __restrict__ sw_g, unsigned short* __restrict__ grb) {
  int g = blockIdx.x * 256 + threadIdx.x;   // 4,194,304
  int hd = g & 511;
  int t = (g >> 9) & 511;
  int b = g >> 18;
  int h = hd >> 6;
  float alpha = 1.f / (1.f + expf(-sw_g[h]));
  int ch = t >> 6, i = t & 63;
  float Ai = exp2f((float)(i + 1) * log2f(alpha));
  float s = tmp[g] + Ai * carry[((size_t)(b * 512 + hd)) * 8 + ch];
  grb[((size_t)(b * 513 + t + 1)) * 512 + hd] = f2b(s);
}

// ---------------------------------------------------------------------------
// LN0: val = res - season - growth ; writes h1 (f32) + h1b (bf16)
// ---------------------------------------------------------------------------
__global__ __launch_bounds__(256) void ln0_kernel(
    const float* __restrict__ res, const float* __restrict__ season,
    const float* __restrict__ growth, const float* __restrict__ g,
    const float* __restrict__ bvec, float* __restrict__ h1,
    unsigned short* __restrict__ h1b) {
  int row = blockIdx.x, b = row >> 9, t = row & 511;
  int tid = threadIdx.x;
  const float* xr = res + (size_t)row * 512;
  const float* sr = season + ((size_t)(b * (Tn + PREDn) + t)) * 512;
  const float* gr = growth + ((size_t)(b * (Tn + 1) + t + 1)) * 512;
  float2 xv = *reinterpret_cast<const float2*>(&xr[tid * 2]);
  float2 sv = *reinterpret_cast<const float2*>(&sr[tid * 2]);
  float2 gv2 = *reinterpret_cast<const float2*>(&gr[tid * 2]);
  float v0 = xv.x - sv.x - gv2.x;
  float v1 = xv.y - sv.y - gv2.y;
  float s1 = v0 + v1;
  float s2 = v0 * v0 + v1 * v1;
  for (int o = 32; o > 0; o >>= 1) {
    s1 += __shfl_down(s1, o, 64);
    s2 += __shfl_down(s2, o, 64);
  }
  __shared__ float r1[4], r2[4];
  __shared__ float mu_s, rstd_s;
  int wv = tid >> 6, ln = tid & 63;
  if (ln == 0) { r1[wv] = s1; r2[wv] = s2; }
  __syncthreads();
  if (tid == 0) {
    float S1 = r1[0] + r1[1] + r1[2] + r1[3];
    float S2 = r2[0] + r2[1] + r2[2] + r2[3];
    float mu = S1 * (1.0f / 512.0f);
    float var = S2 * (1.0f / 512.0f) - mu * mu;
    mu_s = mu;
    rstd_s = rsqrtf(var + 1e-5f);
  }
  __syncthreads();
  float mu = mu_s, rstd = rstd_s;
  float2 gv = *reinterpret_cast<const float2*>(&g[tid * 2]);
  float2 bv = *reinterpret_cast<const float2*>(&bvec[tid * 2]);
  float o0 = (v0 - mu) * rstd * gv.x + bv.x;
  float o1 = (v1 - mu) * rstd * gv.y + bv.y;
  size_t o = (size_t)row * 512 + tid * 2;
  *reinterpret_cast<float2*>(&h1[o]) = make_float2(o0, o1);
  ushort2 hb; hb.x = f2b(o0); hb.y = f2b(o1);
  *reinterpret_cast<ushort2*>(&h1b[o]) = hb;
}

// ---------------------------------------------------------------------------
// LN1: X already holds h1+ff. out = LN(X)*g + b
// ---------------------------------------------------------------------------
__global__ __launch_bounds__(256) void ln1_kernel(
    const float* __restrict__ X, const float* __restrict__ g,
    const float* __restrict__ bvec, float* __restrict__ out) {
  int row = blockIdx.x;
  int tid = threadIdx.x;
  const float* xr = X + (size_t)row * 512;
  float2 xv = *reinterpret_cast<const float2*>(&xr[tid * 2]);
  float v0 = xv.x, v1 = xv.y;
  float s1 = v0 + v1;
  float s2 = v0 * v0 + v1 * v1;
  for (int o = 32; o > 0; o >>= 1) {
    s1 += __shfl_down(s1, o, 64);
    s2 += __shfl_down(s2, o, 64);
  }
  __shared__ float r1[4], r2[4];
  __shared__ float mu_s, rstd_s;
  int wv = tid >> 6, ln = tid & 63;
  if (ln == 0) { r1[wv] = s1; r2[wv] = s2; }
  __syncthreads();
  if (tid == 0) {
    float S1 = r1[0] + r1[1] + r1[2] + r1[3];
    float S2 = r2[0] + r2[1] + r2[2] + r2[3];
    float mu = S1 * (1.0f / 512.0f);
    float var = S2 * (1.0f / 512.0f) - mu * mu;
    mu_s = mu;
    rstd_s = rsqrtf(var + 1e-5f);
  }
  __syncthreads();
  float mu = mu_s, rstd = rstd_s;
  float2 gv = *reinterpret_cast<const float2*>(&g[tid * 2]);
  float2 bv = *reinterpret_cast<const float2*>(&bvec[tid * 2]);
  float o0 = (v0 - mu) * rstd * gv.x + bv.x;
  float o1 = (v1 - mu) * rstd * gv.y + bv.y;
  *reinterpret_cast<float2*>(&out[(size_t)row * 512 + tid * 2]) =
      make_float2(o0, o1);
}

// ---------------------------------------------------------------------------
// 7-wide projection
// ---------------------------------------------------------------------------
__global__ __launch_bounds__(64) void proj7_kernel(
    const float* __restrict__ X, int strB, int off,
    const float* __restrict__ Wc, const float* __restrict__ bc,
    float* __restrict__ outp) {
  int bt = blockIdx.x;
  int b = bt >> 9;
  int t = bt & 511;
  int lane = threadIdx.x;
  const float* row = X + ((size_t)(b * strB + off + t)) * 512;
  float x[8];
#pragma unroll
  for (int i = 0; i < 8; ++i) x[i] = row[lane + 64 * i];
#pragma unroll
  for (int c = 0; c < 7; ++c) {
    float s = 0.f;
#pragma unroll
    for (int i = 0; i < 8; ++i) s += x[i] * Wc[c * 512 + lane + 64 * i];
    for (int o = 32; o > 0; o >>= 1) s += __shfl_down(s, o, 64);
    if (lane == 0) outp[((size_t)bt) * 7 + c] = s + bc[c];
  }
}

// ---------------------------------------------------------------------------
// level EMA via block affine scan. Block = (b,c), 256 thr, 2 t per thread.
// s_t = alpha*s_{t-1} + u_t,  u_t = (1-a)(level-sp) + a*gp,  s_{-1}=v0.
// ---------------------------------------------------------------------------
__global__ __launch_bounds__(256) void lvl_scan(
    const float* __restrict__ level, const float* __restrict__ sp,
    const float* __restrict__ gp, const float* __restrict__ v0_l,
    const float* __restrict__ sw_l, float* __restrict__ out_lvl) {
  int blk = blockIdx.x;           // 0..111
  int b = blk / 7, c = blk % 7;
  int tid = threadIdx.x;
  float alpha = 1.f / (1.f + expf(-sw_l[c]));
  float om = 1.f - alpha;
  size_t i0 = ((size_t)(b * 512 + 2 * tid)) * 7 + c;
  size_t i1 = i0 + 7;
  float u0 = om * (level[i0] - sp[i0]) + alpha * gp[i0];
  float u1 = om * (level[i1] - sp[i1]) + alpha * gp[i1];
  __shared__ float As[256], Us[256];
  As[tid] = alpha * alpha;
  Us[tid] = alpha * u0 + u1;
  __syncthreads();
  for (int off = 1; off < 256; off <<= 1) {
    float Ap = 1.f, Up = 0.f;
    if (tid >= off) { Ap = As[tid - off]; Up = Us[tid - off]; }
    __syncthreads();
    if (tid >= off) {
      float Ac = As[tid], Uc = Us[tid];
      As[tid] = Ac * Ap;
      Us[tid] = Ac * Up + Uc;
    }
    __syncthreads();
  }
  float v0 = v0_l[c];
  float Aex = (tid == 0) ? 1.f : As[tid - 1];
  float Uex = (tid == 0) ? 0.f : Us[tid - 1];
  float sprev = Aex * v0 + Uex;
  float o0 = alpha * sprev + u0;
  float o1 = alpha * o0 + u1;
  out_lvl[i0] = o0;
  out_lvl[i1] = o1;
}

// ---------------------------------------------------------------------------
extern "C" void kernel_launch(void* const* d_in, const int* in_sizes, int n_in,
                              void* d_out, int out_size, void* d_ws,
                              size_t ws_size, hipStream_t stream) {
  const float* res = (const float*)d_in[0];
  const float* level = (const float*)d_in[1];
  const float* Wi = (const float*)d_in[2];
  const float* bi = (const float*)d_in[3];
  const float* z0 = (const float*)d_in[4];
  const float* v0_g = (const float*)d_in[5];
  const float* sw_g = (const float*)d_in[6];
  const float* Wo = (const float*)d_in[7];
  const float* bo = (const float*)d_in[8];
  const float* W1 = (const float*)d_in[9];
  const float* W2 = (const float*)d_in[10];
  const float* g1 = (const float*)d_in[11];
  const float* b1 = (const float*)d_in[12];
  const float* g2 = (const float*)d_in[13];
  const float* b2 = (const float*)d_in[14];
  const float* Wg = (const float*)d_in[15];
  const float* bg = (const float*)d_in[16];
  const float* Wse = (const float*)d_in[17];
  const float* bs = (const float*)d_in[18];
  const float* v0_l = (const float*)d_in[19];
  const float* sw_l = (const float*)d_in[20];

  float* out = (float*)d_out;
  float* out_h = out;                               // 16*512*512
  float* out_lvl = out + 4194304;                   // 16*512*7
  float* out_growth = out + 4251648;                // 16*513*512
  float* out_season = out + 8454144;                // 16*608*512

  float* wsf = (float*)d_ws;
  // A [0, 2,097,152): res1_b -> h1_b -> gpb/spb
  unsigned short* res1_b = (unsigned short*)wsf;
  unsigned short* h1_b = (unsigned short*)wsf;
  float* gpb = wsf;
  float* spb = wsf + 57344;
  // B [2,097,152, 10,485,760):
  unsigned short* resT_b = (unsigned short*)(wsf + 2097152);  // 2,097,152 fl
  float* magb = wsf + 4194304;                                // 2,097,152 fl
  int* candb = (int*)(wsf + 6291456);                         // 262,144 fl
  unsigned short* twc_b = (unsigned short*)(wsf + 6553600);   // 65,536 fl
  unsigned short* tws_b = (unsigned short*)(wsf + 6619136);   // 65,536 fl
  float* vbuf = wsf + 2097152;                                // 4,194,304 fl
  unsigned short* grbuf_b = (unsigned short*)(wsf + 6291456); // 2,101,248 fl
  float* sumend = wsf + 8392704;                              // 65,536 fl
  float* carryb = wsf + 8458240;                              // 65,536 fl
  unsigned short* ff1_b = (unsigned short*)(wsf + 2097152);   // 8,388,608 fl
  // C [10,485,760, 14,680,064):
  double* tabw = (double*)(wsf + 10485760);                   // 2,048 fl
  float* c512 = wsf + 10487808;
  float* s512 = wsf + 10488320;
  int* kidx = (int*)(wsf + 10488832);                         // 131,072
  float* cjb = wsf + 10619904;
  float* sjb = wsf + 10750976;                                // end 10,882,048
  float* tmpb = wsf + 10485760;                               // ema tmp (4.2M fl)
  float* h1 = wsf + 10485760;                                 // 4,194,304 fl
  // D [14,680,064, 15,990,784): bf16 weights
  unsigned short* Wi_b = (unsigned short*)(wsf + 14680064);
  unsigned short* Wo_b = (unsigned short*)(wsf + 14811136);
  unsigned short* W1_b = (unsigned short*)(wsf + 14942208);
  unsigned short* W2_b = (unsigned short*)(wsf + 15466496);

  // 0. weight conversions
  hipLaunchKernelGGL(cvt_bf16, dim3(256), dim3(256), 0, stream, Wi, Wi_b, 262144);
  hipLaunchKernelGGL(cvt_bf16, dim3(256), dim3(256), 0, stream, Wo, Wo_b, 262144);
  hipLaunchKernelGGL(cvt_bf16, dim3(1024), dim3(256), 0, stream, W1, W1_b, 1048576);
  hipLaunchKernelGGL(cvt_bf16, dim3(1024), dim3(256), 0, stream, W2, W2_b, 1048576);

  // 1. season: tables -> transpose -> screen -> cand32 -> refine -> synth
  hipLaunchKernelGGL(twiddle_init2, dim3(512), dim3(256), 0, stream,
                     twc_b, tws_b, tabw, c512, s512);
  hipLaunchKernelGGL(transpose_cvt, dim3(8, 8, 16), dim3(256), 0, stream,
                     res, resT_b);
  hipLaunchKernelGGL(screen_mfma, dim3(4, 4, 16), dim3(256), 0, stream,
                     twc_b, tws_b, resT_b, magb);
  hipLaunchKernelGGL(cand32, dim3(8192), dim3(64), 0, stream, magb, candb);
  hipLaunchKernelGGL(refine32, dim3(32, 16), dim3(512), 0, stream,
                     res, candb, tabw, kidx, cjb, sjb);
  hipLaunchKernelGGL(synth_kernel, dim3(38, 16), dim3(512), 0, stream,
                     kidx, cjb, sjb, c512, s512, res, out_season, res1_b);
  // 2. v = res1 @ Wi^T + bi
  hipLaunchKernelGGL((gemm_mfma<0>), dim3(4, 64), dim3(256), 0, stream,
                     res1_b, Wi_b, bi, vbuf, (unsigned short*)nullptr,
                     8192, 512, 512);
  // 3. growth EMA (3-phase) -> grbuf_b
  hipLaunchKernelGGL(ema_gA, dim3(256), dim3(256), 0, stream,
                     vbuf, z0, sw_g, tmpb, sumend);
  hipLaunchKernelGGL(ema_gB, dim3(32), dim3(256), 0, stream,
                     sumend, v0_g, sw_g, carryb, grbuf_b);
  hipLaunchKernelGGL(ema_gC, dim3(16384), dim3(256), 0, stream,
                     tmpb, carryb, sw_g, grbuf_b);
  // 4. growth = gr @ Wo^T + bo
  hipLaunchKernelGGL((gemm_mfma<0>), dim3(4, 65), dim3(256), 0, stream,
                     grbuf_b, Wo_b, bo, out_growth, (unsigned short*)nullptr,
                     8208, 512, 512);
  // 5. h1 = LN(res - season - growth), + bf16 copy
  hipLaunchKernelGGL(ln0_kernel, dim3(Bn * Tn), dim3(256), 0, stream,
                     res, out_season, out_growth, g1, b1, h1, h1_b);
  // 6. ff1 = relu(h1 @ W1^T) -> bf16
  hipLaunchKernelGGL((gemm_mfma<1>), dim3(16, 64), dim3(256), 0, stream,
                     h1_b, W1_b, (const float*)nullptr, (float*)nullptr, ff1_b,
                     8192, 2048, 512);
  // 7. h1 += ff1 @ W2^T
  hipLaunchKernelGGL((gemm_mfma<2>), dim3(4, 64), dim3(256), 0, stream,
                     ff1_b, W2_b, (const float*)nullptr, h1,
                     (unsigned short*)nullptr, 8192, 512, 2048);
  // 8. h = LN(h1)
  hipLaunchKernelGGL(ln1_kernel, dim3(Bn * Tn), dim3(256), 0, stream,
                     h1, g2, b2, out_h);
  // 9. gp / sp projections
  hipLaunchKernelGGL(proj7_kernel, dim3(Bn * Tn), dim3(64), 0, stream,
                     out_growth, Tn + 1, 1, Wg, bg, gpb);
  hipLaunchKernelGGL(proj7_kernel, dim3(Bn * Tn), dim3(64), 0, stream,
                     out_season, Tn + PREDn, 0, Wse, bs, spb);
  // 10. level EMA (block scan)
  hipLaunchKernelGGL(lvl_scan, dim3(112), dim3(256), 0, stream,
                     level, spb, gpb, v0_l, sw_l, out_lvl);

  (void)in_sizes; (void)n_in; (void)out_size; (void)ws_size;
}